// Round 1
// baseline (884.672 us; speedup 1.0000x reference)
//
#include <hip/hip_runtime.h>
#include <math.h>

// Problem constants (from reference)
#define NN 50000
#define NE 600000
#define NG 64
#define INCH 768
#define HID 128

// ---------------------------------------------------------------------------
// deg / dinv
// ---------------------------------------------------------------------------
__global__ void deg_init(float* dinv) {
    int i = blockIdx.x * blockDim.x + threadIdx.x;
    if (i < NN) dinv[i] = 1.0f;  // self-loop contributes 1 to in-degree
}

__global__ void deg_count(const int* __restrict__ dst, float* dinv) {
    int e = blockIdx.x * blockDim.x + threadIdx.x;
    if (e < NE) atomicAdd(&dinv[dst[e]], 1.0f);
}

__global__ void deg_fin(float* dinv) {
    int i = blockIdx.x * blockDim.x + threadIdx.x;
    if (i < NN) dinv[i] = rsqrtf(dinv[i]);
}

// ---------------------------------------------------------------------------
// condW[g][c] = substring_embed[g] @ W1[768: , c]   (64x128, tiny)
// ---------------------------------------------------------------------------
__global__ void cond_gemm(const float* __restrict__ SE,
                          const float* __restrict__ W1,
                          float* __restrict__ condW) {
    __shared__ float se[INCH];
    int g = blockIdx.x, t = threadIdx.x;
    for (int i = t; i < INCH; i += 128) se[i] = SE[g * INCH + i];
    __syncthreads();
    const float* Wb = W1 + (size_t)INCH * HID;  // rows 768..1535
    float acc = 0.f;
    for (int k = 0; k < INCH; k++)
        acc = fmaf(se[k], Wb[(size_t)k * HID + t], acc);
    condW[g * HID + t] = acc;
}

// ---------------------------------------------------------------------------
// C[M,128] = op(A[M,K]) @ B[K,128]  (+ condW[batch[row]])
// BM=64, BN=128, BK=32, 256 threads, each thread: 8 rows x 4 cols
// ---------------------------------------------------------------------------
template <bool RELU_A, bool ADD_COND>
__global__ __launch_bounds__(256)
void gemm_n128(const float* __restrict__ A, const float* __restrict__ B,
               float* __restrict__ C, const float* __restrict__ condW,
               const int* __restrict__ batch, int M, int K) {
    __shared__ float As[64][33];    // +1 pad: conflict-free scalar broadcast reads
    __shared__ float Bs[32][128];
    const int m0 = blockIdx.x * 64;
    const int t = threadIdx.x;
    const int tr = t >> 5;          // 0..7  (row group)
    const int tc = t & 31;          // 0..31 (col group, 4 cols each)

    float acc[8][4] = {};

    for (int k0 = 0; k0 < K; k0 += 32) {
        // stage A tile: 64x32, 8 elems/thread, coalesced 32 threads/row
#pragma unroll
        for (int rep = 0; rep < 8; rep++) {
            int idx = t + 256 * rep;
            int r = idx >> 5, k = idx & 31;
            int row = m0 + r;
            float v = (row < M) ? A[(size_t)row * K + k0 + k] : 0.0f;
            if (RELU_A) v = fmaxf(v, 0.0f);
            As[r][k] = v;
        }
        // stage B tile: 32x128, 16 elems/thread, coalesced
#pragma unroll
        for (int rep = 0; rep < 16; rep++) {
            int idx = t + 256 * rep;
            int k = idx >> 7, n = idx & 127;
            Bs[k][n] = B[(size_t)(k0 + k) * HID + n];
        }
        __syncthreads();

#pragma unroll
        for (int kk = 0; kk < 32; kk++) {
            float4 b = *(const float4*)&Bs[kk][tc * 4];
#pragma unroll
            for (int j = 0; j < 8; j++) {
                float a = As[tr * 8 + j][kk];   // broadcast within wave
                acc[j][0] = fmaf(a, b.x, acc[j][0]);
                acc[j][1] = fmaf(a, b.y, acc[j][1]);
                acc[j][2] = fmaf(a, b.z, acc[j][2]);
                acc[j][3] = fmaf(a, b.w, acc[j][3]);
            }
        }
        __syncthreads();
    }

#pragma unroll
    for (int j = 0; j < 8; j++) {
        int row = m0 + tr * 8 + j;
        if (row < M) {
            float4 o = make_float4(acc[j][0], acc[j][1], acc[j][2], acc[j][3]);
            if (ADD_COND) {
                int g = batch[row];
                const float* cw = condW + (size_t)g * HID + tc * 4;
                o.x += cw[0]; o.y += cw[1]; o.z += cw[2]; o.w += cw[3];
            }
            *(float4*)&C[(size_t)row * HID + tc * 4] = o;
        }
    }
}

// ---------------------------------------------------------------------------
// aggregation: out[i] = b + t[i]*dinv[i]^2 + sum_{e:dst=i} t[src]*dinv[src]*dinv[dst]
// ---------------------------------------------------------------------------
__global__ void agg_init(const float* __restrict__ t, const float* __restrict__ dinv,
                         const float* __restrict__ bias, float* __restrict__ out) {
    int idx = blockIdx.x * blockDim.x + threadIdx.x;
    if (idx < NN * HID) {
        int i = idx >> 7, c = idx & 127;
        float di = dinv[i];
        out[idx] = fmaf(t[idx], di * di, bias[c]);
    }
}

__global__ void agg_edges(const float* __restrict__ t, const float* __restrict__ dinv,
                          const int* __restrict__ src, const int* __restrict__ dst,
                          float* __restrict__ out) {
    const int total = NE * HID;
    for (int idx = blockIdx.x * blockDim.x + threadIdx.x; idx < total;
         idx += gridDim.x * blockDim.x) {
        int e = idx >> 7, c = idx & 127;
        int s = src[e], d = dst[e];
        float norm = dinv[s] * dinv[d];
        atomicAdd(&out[(size_t)d * HID + c], t[(size_t)s * HID + c] * norm);
    }
}

// ---------------------------------------------------------------------------
// logits[i] = relu(h[i]) @ W_out + b_out   (one wave per node)
// ---------------------------------------------------------------------------
__global__ void out_kernel(const float* __restrict__ h, const float* __restrict__ Wout,
                           const float* __restrict__ bout, float* __restrict__ logits) {
    int gid = blockIdx.x * blockDim.x + threadIdx.x;
    int node = gid >> 6;
    int lane = threadIdx.x & 63;
    if (node >= NN) return;
    const float* row = h + (size_t)node * HID;
    float v = fmaxf(row[lane], 0.f) * Wout[lane] +
              fmaxf(row[lane + 64], 0.f) * Wout[lane + 64];
#pragma unroll
    for (int o = 32; o; o >>= 1) v += __shfl_down(v, o);
    if (lane == 0) logits[node] = v + bout[0];
}

// ---------------------------------------------------------------------------
extern "C" void kernel_launch(void* const* d_in, const int* in_sizes, int n_in,
                              void* d_out, int out_size, void* d_ws, size_t ws_size,
                              hipStream_t stream) {
    const float* x     = (const float*)d_in[0];
    const int*   ei    = (const int*)d_in[1];      // [2, NE] -> src, dst
    const float* se    = (const float*)d_in[2];
    const int*   batch = (const int*)d_in[3];
    const float* W1    = (const float*)d_in[4];    // [1536,128]
    const float* b1    = (const float*)d_in[5];
    const float* W2    = (const float*)d_in[6];    // [128,128]
    const float* b2    = (const float*)d_in[7];
    const float* Wout  = (const float*)d_in[8];    // [128,1]
    const float* bout  = (const float*)d_in[9];
    float* logits = (float*)d_out;

    const int* srcp = ei;
    const int* dstp = ei + NE;

    // workspace layout (floats): dinv | condW | bufA | bufB  (~51.4 MB)
    float* ws    = (float*)d_ws;
    float* dinv  = ws;
    float* condW = ws + 50176;
    float* bufA  = condW + NG * HID;
    float* bufB  = bufA + (size_t)NN * HID;

    // degree -> dinv (shared by both layers)
    deg_init<<<(NN + 255) / 256, 256, 0, stream>>>(dinv);
    deg_count<<<(NE + 255) / 256, 256, 0, stream>>>(dstp, dinv);
    deg_fin<<<(NN + 255) / 256, 256, 0, stream>>>(dinv);

    // conditioning contribution (64 x 128)
    cond_gemm<<<NG, 128, 0, stream>>>(se, W1, condW);

    // layer 1: t1 = x @ W1[:768] + condW[batch]
    gemm_n128<false, true><<<(NN + 63) / 64, 256, 0, stream>>>(
        x, W1, bufA, condW, batch, NN, INCH);
    // aggregate (h1 pre-relu in bufB; relu folded into GEMM2 load)
    agg_init<<<(NN * HID + 255) / 256, 256, 0, stream>>>(bufA, dinv, b1, bufB);
    agg_edges<<<8192, 256, 0, stream>>>(bufA, dinv, srcp, dstp, bufB);

    // layer 2: t2 = relu(h1) @ W2
    gemm_n128<true, false><<<(NN + 63) / 64, 256, 0, stream>>>(
        bufB, W2, bufA, nullptr, nullptr, NN, HID);
    agg_init<<<(NN * HID + 255) / 256, 256, 0, stream>>>(bufA, dinv, b2, bufB);
    agg_edges<<<8192, 256, 0, stream>>>(bufA, dinv, srcp, dstp, bufB);

    // output head
    out_kernel<<<(NN * 64 + 255) / 256, 256, 0, stream>>>(bufB, Wout, bout, logits);
}

// Round 2
// 756.085 us; speedup vs baseline: 1.1701x; 1.1701x over previous
//
#include <hip/hip_runtime.h>
#include <math.h>

#define NN 50000
#define NE 600000
#define NG 64
#define INCH 768
#define HID 128

typedef __attribute__((ext_vector_type(8))) short bf16x8;
typedef __attribute__((ext_vector_type(4))) float f32x4;
typedef unsigned short u16;
typedef unsigned int u32;
typedef unsigned long long u64;

// round-to-nearest-even f32 -> bf16 bits
__device__ __forceinline__ u16 f2bf(float v) {
    u32 u = __builtin_bit_cast(u32, v);
    u32 r = u + 0x7FFFu + ((u >> 16) & 1u);
    return (u16)(r >> 16);
}
__device__ __forceinline__ float bf2f(u16 h) {
    u32 u = ((u32)h) << 16;
    return __builtin_bit_cast(float, u);
}

// ---------------------------------------------------------------------------
// deg / dinv
// ---------------------------------------------------------------------------
__global__ void deg_init(float* dinv) {
    int i = blockIdx.x * blockDim.x + threadIdx.x;
    if (i < NN) dinv[i] = 1.0f;  // self-loop
}
__global__ void deg_count(const int* __restrict__ dst, float* dinv) {
    int e = blockIdx.x * blockDim.x + threadIdx.x;
    if (e < NE) atomicAdd(&dinv[dst[e]], 1.0f);
}
__global__ void deg_fin(float* dinv) {
    int i = blockIdx.x * blockDim.x + threadIdx.x;
    if (i < NN) dinv[i] = rsqrtf(dinv[i]);
}

// ---------------------------------------------------------------------------
// condW[g][c] = substring_embed[g] @ W1[768: , c]   (64x128, tiny, fp32)
// ---------------------------------------------------------------------------
__global__ void cond_gemm(const float* __restrict__ SE,
                          const float* __restrict__ W1,
                          float* __restrict__ condW) {
    __shared__ float se[INCH];
    int g = blockIdx.x, t = threadIdx.x;
    for (int i = t; i < INCH; i += 128) se[i] = SE[g * INCH + i];
    __syncthreads();
    const float* Wb = W1 + (size_t)INCH * HID;
    float acc = 0.f;
    for (int k = 0; k < INCH; k++)
        acc = fmaf(se[k], Wb[(size_t)k * HID + t], acc);
    condW[g * HID + t] = acc;
}

// ---------------------------------------------------------------------------
// W [K][128] fp32 -> Wh/Wl [128][K] bf16 (transposed + hi/lo split)
// ---------------------------------------------------------------------------
__global__ void wt_split(const float* __restrict__ W, u16* __restrict__ Wh,
                         u16* __restrict__ Wl, int K) {
    int idx = blockIdx.x * blockDim.x + threadIdx.x;
    if (idx >= K * HID) return;
    int k = idx >> 7, n = idx & 127;
    float v = W[idx];
    u16 hi = f2bf(v);
    Wh[(size_t)n * K + k] = hi;
    Wl[(size_t)n * K + k] = f2bf(v - bf2f(hi));
}

// ---------------------------------------------------------------------------
// C[M,128] = op(A[M,K]) @ W[K,128]  (+ condW[batch[row]])
// split-bf16 MFMA: A=Ah+Al, B=Bh+Bl; AhBh + AlBh + AhBl.
// 128 threads = 2 waves; BM=64 (32 rows/wave); B frags straight from L2.
// ---------------------------------------------------------------------------
template <bool RELU_A, bool ADD_COND>
__global__ __launch_bounds__(128)
void mfma_gemm(const float* __restrict__ A, const u16* __restrict__ Wh,
               const u16* __restrict__ Wl, float* __restrict__ C,
               const float* __restrict__ condW, const int* __restrict__ batch,
               int M, int K) {
    __shared__ u16 Ah[64 * 40];   // padded stride 40 -> 2-way (free) on b128 reads
    __shared__ u16 Al[64 * 40];
    const int m0 = blockIdx.x * 64;
    const int t = threadIdx.x;
    const int w = t >> 6;         // wave 0..1
    const int l = t & 63;
    const int l16 = l & 15;
    const int lq = l >> 4;        // 0..3

    f32x4 acc[2][8] = {};

    for (int k0 = 0; k0 < K; k0 += 32) {
        // stage 64x32 fp32 tile -> split bf16 in LDS (4 float4 per thread)
#pragma unroll
        for (int rep = 0; rep < 4; rep++) {
            int idx = t + 128 * rep;          // 0..511
            int row = idx >> 3, c4 = idx & 7;
            int grow = m0 + row;
            float4 v = make_float4(0.f, 0.f, 0.f, 0.f);
            if (grow < M) v = *(const float4*)&A[(size_t)grow * K + k0 + c4 * 4];
            if (RELU_A) {
                v.x = fmaxf(v.x, 0.f); v.y = fmaxf(v.y, 0.f);
                v.z = fmaxf(v.z, 0.f); v.w = fmaxf(v.w, 0.f);
            }
            u16 h0 = f2bf(v.x), h1 = f2bf(v.y), h2 = f2bf(v.z), h3 = f2bf(v.w);
            u16 e0 = f2bf(v.x - bf2f(h0)), e1 = f2bf(v.y - bf2f(h1));
            u16 e2 = f2bf(v.z - bf2f(h2)), e3 = f2bf(v.w - bf2f(h3));
            int off = row * 40 + c4 * 4;
            *(u64*)&Ah[off] = (u64)h0 | ((u64)h1 << 16) | ((u64)h2 << 32) | ((u64)h3 << 48);
            *(u64*)&Al[off] = (u64)e0 | ((u64)e1 << 16) | ((u64)e2 << 32) | ((u64)e3 << 48);
        }
        __syncthreads();

        // A fragments: row = wave*32 + 16m + (l&15), k-chunk = lq*8..+8 (one b128)
        bf16x8 ah[2], al[2];
#pragma unroll
        for (int m = 0; m < 2; m++) {
            int off = (w * 32 + m * 16 + l16) * 40 + lq * 8;
            ah[m] = *(const bf16x8*)&Ah[off];
            al[m] = *(const bf16x8*)&Al[off];
        }

        // B fragments direct from global (L2-resident) + MFMA
#pragma unroll
        for (int f = 0; f < 8; f++) {
            size_t boff = (size_t)(f * 16 + l16) * K + k0 + lq * 8;
            bf16x8 bh = *(const bf16x8*)&Wh[boff];
            bf16x8 bl = *(const bf16x8*)&Wl[boff];
#pragma unroll
            for (int m = 0; m < 2; m++) {
                acc[m][f] = __builtin_amdgcn_mfma_f32_16x16x32_bf16(ah[m], bh, acc[m][f], 0, 0, 0);
                acc[m][f] = __builtin_amdgcn_mfma_f32_16x16x32_bf16(al[m], bh, acc[m][f], 0, 0, 0);
                acc[m][f] = __builtin_amdgcn_mfma_f32_16x16x32_bf16(ah[m], bl, acc[m][f], 0, 0, 0);
            }
        }
        __syncthreads();  // protect LDS from next iteration's staging
    }

    // epilogue: C row = m0 + w*32 + 16m + lq*4 + j, col = f*16 + (l&15)
#pragma unroll
    for (int m = 0; m < 2; m++) {
#pragma unroll
        for (int j = 0; j < 4; j++) {
            int grow = m0 + w * 32 + m * 16 + lq * 4 + j;
            if (grow < M) {
                int gb = 0;
                if (ADD_COND) gb = batch[grow];
#pragma unroll
                for (int f = 0; f < 8; f++) {
                    int gcol = f * 16 + l16;
                    float v = acc[m][f][j];
                    if (ADD_COND) v += condW[gb * HID + gcol];
                    C[(size_t)grow * HID + gcol] = v;
                }
            }
        }
    }
}

// ---------------------------------------------------------------------------
// aggregation: out[i] = b + t[i]*dinv[i]^2 + sum_{e:dst=i} t[src]*dinv[src]*dinv[dst]
// ---------------------------------------------------------------------------
__global__ void agg_init(const float* __restrict__ t, const float* __restrict__ dinv,
                         const float* __restrict__ bias, float* __restrict__ out) {
    int idx = blockIdx.x * blockDim.x + threadIdx.x;
    if (idx < NN * HID) {
        int i = idx >> 7, c = idx & 127;
        float di = dinv[i];
        out[idx] = fmaf(t[idx], di * di, bias[c]);
    }
}

__global__ void agg_edges(const float* __restrict__ t, const float* __restrict__ dinv,
                          const int* __restrict__ src, const int* __restrict__ dst,
                          float* __restrict__ out) {
    const int total = NE * HID;
    for (int idx = blockIdx.x * blockDim.x + threadIdx.x; idx < total;
         idx += gridDim.x * blockDim.x) {
        int e = idx >> 7, c = idx & 127;
        int s = src[e], d = dst[e];
        float norm = dinv[s] * dinv[d];
        atomicAdd(&out[(size_t)d * HID + c], t[(size_t)s * HID + c] * norm);
    }
}

// ---------------------------------------------------------------------------
// logits[i] = relu(h[i]) @ W_out + b_out   (one wave per node)
// ---------------------------------------------------------------------------
__global__ void out_kernel(const float* __restrict__ h, const float* __restrict__ Wout,
                           const float* __restrict__ bout, float* __restrict__ logits) {
    int gid = blockIdx.x * blockDim.x + threadIdx.x;
    int node = gid >> 6;
    int lane = threadIdx.x & 63;
    if (node >= NN) return;
    const float* row = h + (size_t)node * HID;
    float v = fmaxf(row[lane], 0.f) * Wout[lane] +
              fmaxf(row[lane + 64], 0.f) * Wout[lane + 64];
#pragma unroll
    for (int o = 32; o; o >>= 1) v += __shfl_down(v, o);
    if (lane == 0) logits[node] = v + bout[0];
}

// ---------------------------------------------------------------------------
extern "C" void kernel_launch(void* const* d_in, const int* in_sizes, int n_in,
                              void* d_out, int out_size, void* d_ws, size_t ws_size,
                              hipStream_t stream) {
    const float* x     = (const float*)d_in[0];
    const int*   ei    = (const int*)d_in[1];
    const float* se    = (const float*)d_in[2];
    const int*   batch = (const int*)d_in[3];
    const float* W1    = (const float*)d_in[4];
    const float* b1    = (const float*)d_in[5];
    const float* W2    = (const float*)d_in[6];
    const float* b2    = (const float*)d_in[7];
    const float* Wout  = (const float*)d_in[8];
    const float* bout  = (const float*)d_in[9];
    float* logits = (float*)d_out;

    const int* srcp = ei;
    const int* dstp = ei + NE;

    // workspace carve (floats; all offsets 16B-aligned)
    float* ws    = (float*)d_ws;
    float* dinv  = ws;                                  // 50176
    float* condW = ws + 50176;                          // 8192
    u16*   W1h   = (u16*)(ws + 58368);                  // 98304 u16 = 49152 f
    u16*   W1l   = (u16*)(ws + 58368 + 49152);          // 49152 f
    u16*   W2h   = (u16*)(ws + 58368 + 98304);          // 8192 f
    u16*   W2l   = (u16*)(ws + 58368 + 98304 + 8192);   // 8192 f
    float* bufA  = ws + 58368 + 98304 + 16384;          // 6400000 f
    float* bufB  = bufA + (size_t)NN * HID;

    // degree -> dinv
    deg_init<<<(NN + 255) / 256, 256, 0, stream>>>(dinv);
    deg_count<<<(NE + 255) / 256, 256, 0, stream>>>(dstp, dinv);
    deg_fin<<<(NN + 255) / 256, 256, 0, stream>>>(dinv);

    // weight prep (tiny)
    cond_gemm<<<NG, 128, 0, stream>>>(se, W1, condW);
    wt_split<<<(INCH * HID + 255) / 256, 256, 0, stream>>>(W1, W1h, W1l, INCH);
    wt_split<<<(HID * HID + 255) / 256, 256, 0, stream>>>(W2, W2h, W2l, HID);

    // layer 1: t1 = x @ W1[:768] + condW[batch]
    mfma_gemm<false, true><<<(NN + 63) / 64, 128, 0, stream>>>(
        x, W1h, W1l, bufA, condW, batch, NN, INCH);
    agg_init<<<(NN * HID + 255) / 256, 256, 0, stream>>>(bufA, dinv, b1, bufB);
    agg_edges<<<8192, 256, 0, stream>>>(bufA, dinv, srcp, dstp, bufB);

    // layer 2: t2 = relu(h1) @ W2
    mfma_gemm<true, false><<<(NN + 63) / 64, 128, 0, stream>>>(
        bufB, W2h, W2l, bufA, nullptr, nullptr, NN, HID);
    agg_init<<<(NN * HID + 255) / 256, 256, 0, stream>>>(bufA, dinv, b2, bufB);
    agg_edges<<<8192, 256, 0, stream>>>(bufA, dinv, srcp, dstp, bufB);

    // output head
    out_kernel<<<(NN * 64 + 255) / 256, 256, 0, stream>>>(bufB, Wout, bout, logits);
}

// Round 3
// 401.922 us; speedup vs baseline: 2.2011x; 1.8812x over previous
//
#include <hip/hip_runtime.h>
#include <math.h>

#define NN 50000
#define NE 600000
#define NG 64
#define INCH 768
#define HID 128

typedef __attribute__((ext_vector_type(8))) short bf16x8;
typedef __attribute__((ext_vector_type(4))) float f32x4;
typedef unsigned short u16;
typedef unsigned int u32;
typedef unsigned long long u64;

__device__ __forceinline__ u16 f2bf(float v) {
    u32 u = __builtin_bit_cast(u32, v);
    u32 r = u + 0x7FFFu + ((u >> 16) & 1u);
    return (u16)(r >> 16);
}
__device__ __forceinline__ float bf2f(u16 h) {
    u32 u = ((u32)h) << 16;
    return __builtin_bit_cast(float, u);
}

// ---------------------------------------------------------------------------
// degree counts (int) -> dinv
// ---------------------------------------------------------------------------
__global__ void zero_counts(int* counts) {
    int i = blockIdx.x * blockDim.x + threadIdx.x;
    if (i < NN) counts[i] = 0;
}
__global__ void deg_count(const int* __restrict__ dst, int* counts) {
    int e = blockIdx.x * blockDim.x + threadIdx.x;
    if (e < NE) atomicAdd(&counts[dst[e]], 1);
}
__global__ void deg_fin(const int* __restrict__ counts, float* dinv) {
    int i = blockIdx.x * blockDim.x + threadIdx.x;
    if (i < NN) dinv[i] = rsqrtf((float)counts[i] + 1.0f);  // +1 self-loop
}

// ---------------------------------------------------------------------------
// CSR build: exclusive scan of counts -> row_start, then scatter-fill csr_src
// ---------------------------------------------------------------------------
__global__ void pscan1(const int* __restrict__ counts, int* __restrict__ row_start,
                       int* __restrict__ bsum) {
    __shared__ int sm[256];
    int t = threadIdx.x;
    int i = blockIdx.x * 256 + t;
    int v = (i < NN) ? counts[i] : 0;
    sm[t] = v;
    __syncthreads();
#pragma unroll
    for (int off = 1; off < 256; off <<= 1) {
        int add = (t >= off) ? sm[t - off] : 0;
        __syncthreads();
        sm[t] += add;
        __syncthreads();
    }
    row_start[i] = sm[t] - v;             // exclusive
    if (t == 255) bsum[blockIdx.x] = sm[t];
}

__global__ void pscan2(int* bsum, int nb) {
    __shared__ int sm[256];
    int t = threadIdx.x;
    int v = (t < nb) ? bsum[t] : 0;
    sm[t] = v;
    __syncthreads();
#pragma unroll
    for (int off = 1; off < 256; off <<= 1) {
        int add = (t >= off) ? sm[t - off] : 0;
        __syncthreads();
        sm[t] += add;
        __syncthreads();
    }
    if (t < nb) bsum[t] = sm[t] - v;      // exclusive
}

__global__ void pscan3(int* __restrict__ row_start, const int* __restrict__ bsum,
                       int* __restrict__ cursor) {
    int i = blockIdx.x * 256 + threadIdx.x;
    int v = row_start[i] + bsum[blockIdx.x];
    row_start[i] = v;                     // index NN (=50000) included (grid covers 50176)
    if (i < NN) cursor[i] = v;
}

__global__ void csr_fill(const int* __restrict__ src, const int* __restrict__ dst,
                         int* __restrict__ cursor, int* __restrict__ csr_src) {
    int e = blockIdx.x * blockDim.x + threadIdx.x;
    if (e < NE) {
        int pos = atomicAdd(&cursor[dst[e]], 1);
        csr_src[pos] = src[e];
    }
}

// ---------------------------------------------------------------------------
// condW[g][c] = substring_embed[g] @ W1[768: , c]
// ---------------------------------------------------------------------------
__global__ void cond_gemm(const float* __restrict__ SE,
                          const float* __restrict__ W1,
                          float* __restrict__ condW) {
    __shared__ float se[INCH];
    int g = blockIdx.x, t = threadIdx.x;
    for (int i = t; i < INCH; i += 128) se[i] = SE[g * INCH + i];
    __syncthreads();
    const float* Wb = W1 + (size_t)INCH * HID;
    float acc = 0.f;
    for (int k = 0; k < INCH; k++)
        acc = fmaf(se[k], Wb[(size_t)k * HID + t], acc);
    condW[g * HID + t] = acc;
}

// ---------------------------------------------------------------------------
// W [K][128] fp32 -> Wh/Wl [128][K] bf16 (transposed + hi/lo split)
// ---------------------------------------------------------------------------
__global__ void wt_split(const float* __restrict__ W, u16* __restrict__ Wh,
                         u16* __restrict__ Wl, int K) {
    int idx = blockIdx.x * blockDim.x + threadIdx.x;
    if (idx >= K * HID) return;
    int k = idx >> 7, n = idx & 127;
    float v = W[idx];
    u16 hi = f2bf(v);
    Wh[(size_t)n * K + k] = hi;
    Wl[(size_t)n * K + k] = f2bf(v - bf2f(hi));
}

// ---------------------------------------------------------------------------
// u[M,128] = (op(A) @ W + cond) * dinv[row]   via split-bf16 MFMA
// ---------------------------------------------------------------------------
template <bool RELU_A, bool ADD_COND>
__global__ __launch_bounds__(128)
void mfma_gemm(const float* __restrict__ A, const u16* __restrict__ Wh,
               const u16* __restrict__ Wl, float* __restrict__ C,
               const float* __restrict__ condW, const int* __restrict__ batch,
               const float* __restrict__ dinv, int M, int K) {
    __shared__ u16 Ah[64 * 40];
    __shared__ u16 Al[64 * 40];
    const int m0 = blockIdx.x * 64;
    const int t = threadIdx.x;
    const int w = t >> 6;
    const int l = t & 63;
    const int l16 = l & 15;
    const int lq = l >> 4;

    f32x4 acc[2][8] = {};

    for (int k0 = 0; k0 < K; k0 += 32) {
#pragma unroll
        for (int rep = 0; rep < 4; rep++) {
            int idx = t + 128 * rep;
            int row = idx >> 3, c4 = idx & 7;
            int grow = m0 + row;
            float4 v = make_float4(0.f, 0.f, 0.f, 0.f);
            if (grow < M) v = *(const float4*)&A[(size_t)grow * K + k0 + c4 * 4];
            if (RELU_A) {
                v.x = fmaxf(v.x, 0.f); v.y = fmaxf(v.y, 0.f);
                v.z = fmaxf(v.z, 0.f); v.w = fmaxf(v.w, 0.f);
            }
            u16 h0 = f2bf(v.x), h1 = f2bf(v.y), h2 = f2bf(v.z), h3 = f2bf(v.w);
            u16 e0 = f2bf(v.x - bf2f(h0)), e1 = f2bf(v.y - bf2f(h1));
            u16 e2 = f2bf(v.z - bf2f(h2)), e3 = f2bf(v.w - bf2f(h3));
            int off = row * 40 + c4 * 4;
            *(u64*)&Ah[off] = (u64)h0 | ((u64)h1 << 16) | ((u64)h2 << 32) | ((u64)h3 << 48);
            *(u64*)&Al[off] = (u64)e0 | ((u64)e1 << 16) | ((u64)e2 << 32) | ((u64)e3 << 48);
        }
        __syncthreads();

        bf16x8 ah[2], al[2];
#pragma unroll
        for (int m = 0; m < 2; m++) {
            int off = (w * 32 + m * 16 + l16) * 40 + lq * 8;
            ah[m] = *(const bf16x8*)&Ah[off];
            al[m] = *(const bf16x8*)&Al[off];
        }

#pragma unroll
        for (int f = 0; f < 8; f++) {
            size_t boff = (size_t)(f * 16 + l16) * K + k0 + lq * 8;
            bf16x8 bh = *(const bf16x8*)&Wh[boff];
            bf16x8 bl = *(const bf16x8*)&Wl[boff];
#pragma unroll
            for (int m = 0; m < 2; m++) {
                acc[m][f] = __builtin_amdgcn_mfma_f32_16x16x32_bf16(ah[m], bh, acc[m][f], 0, 0, 0);
                acc[m][f] = __builtin_amdgcn_mfma_f32_16x16x32_bf16(al[m], bh, acc[m][f], 0, 0, 0);
                acc[m][f] = __builtin_amdgcn_mfma_f32_16x16x32_bf16(ah[m], bl, acc[m][f], 0, 0, 0);
            }
        }
        __syncthreads();
    }

#pragma unroll
    for (int m = 0; m < 2; m++) {
#pragma unroll
        for (int j = 0; j < 4; j++) {
            int grow = m0 + w * 32 + m * 16 + lq * 4 + j;
            if (grow < M) {
                float scale = dinv[grow];
                int gb = 0;
                if (ADD_COND) gb = batch[grow];
#pragma unroll
                for (int f = 0; f < 8; f++) {
                    int gcol = f * 16 + l16;
                    float v = acc[m][f][j];
                    if (ADD_COND) v += condW[gb * HID + gcol];
                    C[(size_t)grow * HID + gcol] = v * scale;
                }
            }
        }
    }
}

// ---------------------------------------------------------------------------
// gather aggregation: out[d] = bias + dinv[d] * (u[d] + sum_{e: dst=d} u[src])
// one wave per node, float2 per lane (64 lanes x 8B = 512B row)
// ---------------------------------------------------------------------------
__global__ __launch_bounds__(256)
void agg_gather(const float* __restrict__ u, const float* __restrict__ dinv,
                const int* __restrict__ row_start, const int* __restrict__ csr_src,
                const float* __restrict__ bias, float* __restrict__ out) {
    int node = blockIdx.x * 4 + (threadIdx.x >> 6);
    int lane = threadIdx.x & 63;
    if (node >= NN) return;
    int p = row_start[node], pend = row_start[node + 1];
    float2 acc = *(const float2*)&u[(size_t)node * HID + lane * 2];
    int s = (p < pend) ? csr_src[p] : 0;
    while (p < pend) {
        int sn = (p + 1 < pend) ? csr_src[p + 1] : 0;
        float2 v = *(const float2*)&u[(size_t)s * HID + lane * 2];
        acc.x += v.x;
        acc.y += v.y;
        s = sn;
        ++p;
    }
    float dd = dinv[node];
    float2 bb = *(const float2*)&bias[lane * 2];
    float2 o;
    o.x = fmaf(dd, acc.x, bb.x);
    o.y = fmaf(dd, acc.y, bb.y);
    *(float2*)&out[(size_t)node * HID + lane * 2] = o;
}

// ---------------------------------------------------------------------------
// logits[i] = relu(h[i]) @ W_out + b_out
// ---------------------------------------------------------------------------
__global__ void out_kernel(const float* __restrict__ h, const float* __restrict__ Wout,
                           const float* __restrict__ bout, float* __restrict__ logits) {
    int gid = blockIdx.x * blockDim.x + threadIdx.x;
    int node = gid >> 6;
    int lane = threadIdx.x & 63;
    if (node >= NN) return;
    const float* row = h + (size_t)node * HID;
    float v = fmaxf(row[lane], 0.f) * Wout[lane] +
              fmaxf(row[lane + 64], 0.f) * Wout[lane + 64];
#pragma unroll
    for (int o = 32; o; o >>= 1) v += __shfl_down(v, o);
    if (lane == 0) logits[node] = v + bout[0];
}

// ---------------------------------------------------------------------------
extern "C" void kernel_launch(void* const* d_in, const int* in_sizes, int n_in,
                              void* d_out, int out_size, void* d_ws, size_t ws_size,
                              hipStream_t stream) {
    const float* x     = (const float*)d_in[0];
    const int*   ei    = (const int*)d_in[1];
    const float* se    = (const float*)d_in[2];
    const int*   batch = (const int*)d_in[3];
    const float* W1    = (const float*)d_in[4];
    const float* b1    = (const float*)d_in[5];
    const float* W2    = (const float*)d_in[6];
    const float* b2    = (const float*)d_in[7];
    const float* Wout  = (const float*)d_in[8];
    const float* bout  = (const float*)d_in[9];
    float* logits = (float*)d_out;

    const int* srcp = ei;
    const int* dstp = ei + NE;

    // workspace carve (float offsets from base; all 16B-aligned)
    float* ws       = (float*)d_ws;
    float* dinv     = ws;                        // 50176
    float* condW    = ws + 50176;                // 8192
    u16*   W1h      = (u16*)(ws + 58368);        // 49152 f
    u16*   W1l      = (u16*)(ws + 107520);       // 49152 f
    u16*   W2h      = (u16*)(ws + 156672);       // 8192 f
    u16*   W2l      = (u16*)(ws + 164864);       // 8192 f
    int*   counts   = (int*)(ws + 173056);       // 50176 (reused as cursor)
    int*   row_st   = (int*)(ws + 223232);       // 50176
    int*   csr_src  = (int*)(ws + 273408);       // 600000
    int*   bsum     = (int*)(ws + 873408);       // 256
    float* bufA     = ws + 873664;               // 6.4M
    float* bufB     = bufA + (size_t)NN * HID;   // 6.4M  (end ~54.7 MB)

    const int NB = (NN + 255) / 256;  // 196 blocks covering 50176

    // degree + CSR build (structure shared by both layers)
    zero_counts<<<NB, 256, 0, stream>>>(counts);
    deg_count<<<(NE + 255) / 256, 256, 0, stream>>>(dstp, counts);
    deg_fin<<<NB, 256, 0, stream>>>(counts, dinv);
    pscan1<<<NB, 256, 0, stream>>>(counts, row_st, bsum);
    pscan2<<<1, 256, 0, stream>>>(bsum, NB);
    pscan3<<<NB, 256, 0, stream>>>(row_st, bsum, counts);
    csr_fill<<<(NE + 255) / 256, 256, 0, stream>>>(srcp, dstp, counts, csr_src);

    // weight prep
    cond_gemm<<<NG, 128, 0, stream>>>(se, W1, condW);
    wt_split<<<(INCH * HID + 255) / 256, 256, 0, stream>>>(W1, W1h, W1l, INCH);
    wt_split<<<(HID * HID + 255) / 256, 256, 0, stream>>>(W2, W2h, W2l, HID);

    // layer 1: u1 = (x @ W1[:768] + condW[batch]) * dinv
    mfma_gemm<false, true><<<(NN + 63) / 64, 128, 0, stream>>>(
        x, W1h, W1l, bufA, condW, batch, dinv, NN, INCH);
    agg_gather<<<(NN + 3) / 4, 256, 0, stream>>>(bufA, dinv, row_st, csr_src, b1, bufB);

    // layer 2: u2 = (relu(h1) @ W2) * dinv
    mfma_gemm<true, false><<<(NN + 63) / 64, 128, 0, stream>>>(
        bufB, W2h, W2l, bufA, nullptr, nullptr, dinv, NN, HID);
    agg_gather<<<(NN + 3) / 4, 256, 0, stream>>>(bufA, dinv, row_st, csr_src, b2, bufB);

    // output head
    out_kernel<<<(NN * 64 + 255) / 256, 256, 0, stream>>>(bufB, Wout, bout, logits);
}

// Round 4
// 337.442 us; speedup vs baseline: 2.6217x; 1.1911x over previous
//
#include <hip/hip_runtime.h>
#include <math.h>

#define NN 50000
#define NE 600000
#define NG 64
#define INCH 768
#define HID 128

typedef __attribute__((ext_vector_type(8))) short bf16x8;
typedef __attribute__((ext_vector_type(4))) float f32x4;
typedef __attribute__((ext_vector_type(4))) unsigned int u32x4;
typedef unsigned short u16;
typedef unsigned int u32;
typedef unsigned long long u64;

__device__ __forceinline__ u16 f2bf(float v) {
    u32 u = __builtin_bit_cast(u32, v);
    u32 r = u + 0x7FFFu + ((u >> 16) & 1u);
    return (u16)(r >> 16);
}
__device__ __forceinline__ float bf2f(u16 h) {
    u32 u = ((u32)h) << 16;
    return __builtin_bit_cast(float, u);
}
// packed RTNE: low16 = bf16(a), high16 = bf16(b)
__device__ __forceinline__ u32 cvtpk(float a, float b) {
    u32 r;
    asm("v_cvt_pk_bf16_f32 %0, %1, %2" : "=v"(r) : "v"(a), "v"(b));
    return r;
}

// ---------------------------------------------------------------------------
// degree counts (int) -> dinv
// ---------------------------------------------------------------------------
__global__ void zero_counts(int* counts) {
    int i = blockIdx.x * blockDim.x + threadIdx.x;
    if (i < NN) counts[i] = 0;
}
__global__ void deg_count(const int* __restrict__ dst, int* counts) {
    int e = blockIdx.x * blockDim.x + threadIdx.x;
    if (e < NE) atomicAdd(&counts[dst[e]], 1);
}
__global__ void deg_fin(const int* __restrict__ counts, float* dinv) {
    int i = blockIdx.x * blockDim.x + threadIdx.x;
    if (i < NN) dinv[i] = rsqrtf((float)counts[i] + 1.0f);  // +1 self-loop
}

// ---------------------------------------------------------------------------
// CSR build
// ---------------------------------------------------------------------------
__global__ void pscan1(const int* __restrict__ counts, int* __restrict__ row_start,
                       int* __restrict__ bsum) {
    __shared__ int sm[256];
    int t = threadIdx.x;
    int i = blockIdx.x * 256 + t;
    int v = (i < NN) ? counts[i] : 0;
    sm[t] = v;
    __syncthreads();
#pragma unroll
    for (int off = 1; off < 256; off <<= 1) {
        int add = (t >= off) ? sm[t - off] : 0;
        __syncthreads();
        sm[t] += add;
        __syncthreads();
    }
    row_start[i] = sm[t] - v;
    if (t == 255) bsum[blockIdx.x] = sm[t];
}

__global__ void pscan2(int* bsum, int nb) {
    __shared__ int sm[256];
    int t = threadIdx.x;
    int v = (t < nb) ? bsum[t] : 0;
    sm[t] = v;
    __syncthreads();
#pragma unroll
    for (int off = 1; off < 256; off <<= 1) {
        int add = (t >= off) ? sm[t - off] : 0;
        __syncthreads();
        sm[t] += add;
        __syncthreads();
    }
    if (t < nb) bsum[t] = sm[t] - v;
}

__global__ void pscan3(int* __restrict__ row_start, const int* __restrict__ bsum,
                       int* __restrict__ cursor) {
    int i = blockIdx.x * 256 + threadIdx.x;
    int v = row_start[i] + bsum[blockIdx.x];
    row_start[i] = v;
    if (i < NN) cursor[i] = v;
}

__global__ void csr_fill(const int* __restrict__ src, const int* __restrict__ dst,
                         int* __restrict__ cursor, int* __restrict__ csr_src) {
    int e = blockIdx.x * blockDim.x + threadIdx.x;
    if (e < NE) {
        int pos = atomicAdd(&cursor[dst[e]], 1);
        csr_src[pos] = src[e];
    }
}

// ---------------------------------------------------------------------------
// condW[g][c] = substring_embed[g] @ W1[768: , c]
// ---------------------------------------------------------------------------
__global__ void cond_gemm(const float* __restrict__ SE,
                          const float* __restrict__ W1,
                          float* __restrict__ condW) {
    __shared__ float se[INCH];
    int g = blockIdx.x, t = threadIdx.x;
    for (int i = t; i < INCH; i += 128) se[i] = SE[g * INCH + i];
    __syncthreads();
    const float* Wb = W1 + (size_t)INCH * HID;
    float acc = 0.f;
    for (int k = 0; k < INCH; k++)
        acc = fmaf(se[k], Wb[(size_t)k * HID + t], acc);
    condW[g * HID + t] = acc;
}

// ---------------------------------------------------------------------------
// Pack W [K][128] fp32 into MFMA-fragment order, split hi/lo bf16:
// P[c][hl][f][lane][e]  (c = k0/32 chunk, f = 16-col group, e = 0..7)
// lane l supplies col = f*16 + (l&15), k = c*32 + (l>>4)*8 + e.
// Per (c,hl,f) a wave's 64 lanes read one contiguous 1KB line.
// ---------------------------------------------------------------------------
__global__ void wt_pack(const float* __restrict__ W, u16* __restrict__ P, int K) {
    int tid = blockIdx.x * blockDim.x + threadIdx.x;
    int total = (K / 32) * 512;          // (c,f,l) triples
    if (tid >= total) return;
    int l = tid & 63;
    int f = (tid >> 6) & 7;
    int c = tid >> 9;
    int n = f * 16 + (l & 15);
    int kb = c * 32 + ((l >> 4) & 3) * 8;
    u64 h0 = 0, h1 = 0, l0 = 0, l1 = 0;
#pragma unroll
    for (int e = 0; e < 8; e++) {
        float v = W[(size_t)(kb + e) * HID + n];
        u16 h = f2bf(v);
        u16 r = f2bf(v - bf2f(h));
        if (e < 4) { h0 |= (u64)h << (16 * e);       l0 |= (u64)r << (16 * e); }
        else       { h1 |= (u64)h << (16 * (e - 4)); l1 |= (u64)r << (16 * (e - 4)); }
    }
    size_t base = (size_t)c * 8192 + (size_t)f * 512 + l * 8;
    *(u64*)&P[base]          = h0;
    *(u64*)&P[base + 4]      = h1;
    *(u64*)&P[base + 4096]   = l0;
    *(u64*)&P[base + 4100]   = l1;
}

// ---------------------------------------------------------------------------
// u[M,128] = (op(A) @ W + cond) * dinv[row]
// Barrier-free split-bf16 MFMA: 16 rows/wave, A direct global->reg with
// register double-buffer; B from packed fragments (L1-broadcast).
// ---------------------------------------------------------------------------
template <int K, bool RELU_A, bool ADD_COND>
__global__ __launch_bounds__(256, 3)
void mfma_gemm(const float* __restrict__ A, const u16* __restrict__ P,
               float* __restrict__ C, const float* __restrict__ condW,
               const int* __restrict__ batch, const float* __restrict__ dinv,
               int M) {
    const int t = threadIdx.x;
    const int w = t >> 6;
    const int l = t & 63;
    const int l16 = l & 15;
    const int lq = l >> 4;
    const int m0 = blockIdx.x * 64;
    const int arow = m0 + w * 16 + l16;
    const bool rowok = arow < M;
    const float* Ap = A + (size_t)(rowok ? arow : 0) * K + lq * 8;
    const u16* Pl = P + l * 8;

    f32x4 acc[8] = {};
    float4 a0, a1;
    if (rowok) {
        a0 = *(const float4*)Ap;
        a1 = *(const float4*)(Ap + 4);
    } else {
        a0 = make_float4(0.f, 0.f, 0.f, 0.f);
        a1 = a0;
    }

    constexpr int NC = K / 32;
    for (int c = 0; c < NC; ++c) {
        // prefetch next A chunk
        float4 n0, n1;
        if (c + 1 < NC && rowok) {
            n0 = *(const float4*)(Ap + 32 * (c + 1));
            n1 = *(const float4*)(Ap + 32 * (c + 1) + 4);
        } else {
            n0 = make_float4(0.f, 0.f, 0.f, 0.f);
            n1 = n0;
        }

        float4 b0 = a0, b1 = a1;
        if (RELU_A) {
            b0.x = fmaxf(b0.x, 0.f); b0.y = fmaxf(b0.y, 0.f);
            b0.z = fmaxf(b0.z, 0.f); b0.w = fmaxf(b0.w, 0.f);
            b1.x = fmaxf(b1.x, 0.f); b1.y = fmaxf(b1.y, 0.f);
            b1.z = fmaxf(b1.z, 0.f); b1.w = fmaxf(b1.w, 0.f);
        }
        // RTNE split: hi via cvt_pk, residual, lo via cvt_pk
        u32 h0 = cvtpk(b0.x, b0.y), h1 = cvtpk(b0.z, b0.w);
        u32 h2 = cvtpk(b1.x, b1.y), h3 = cvtpk(b1.z, b1.w);
        float r0 = b0.x - __builtin_bit_cast(float, h0 << 16);
        float r1 = b0.y - __builtin_bit_cast(float, h0 & 0xFFFF0000u);
        float r2 = b0.z - __builtin_bit_cast(float, h1 << 16);
        float r3 = b0.w - __builtin_bit_cast(float, h1 & 0xFFFF0000u);
        float r4 = b1.x - __builtin_bit_cast(float, h2 << 16);
        float r5 = b1.y - __builtin_bit_cast(float, h2 & 0xFFFF0000u);
        float r6 = b1.z - __builtin_bit_cast(float, h3 << 16);
        float r7 = b1.w - __builtin_bit_cast(float, h3 & 0xFFFF0000u);
        u32 e0 = cvtpk(r0, r1), e1 = cvtpk(r2, r3);
        u32 e2 = cvtpk(r4, r5), e3 = cvtpk(r6, r7);
        bf16x8 ah = __builtin_bit_cast(bf16x8, (u32x4){h0, h1, h2, h3});
        bf16x8 al = __builtin_bit_cast(bf16x8, (u32x4){e0, e1, e2, e3});

        const u16* Bc = Pl + (size_t)c * 8192;
#pragma unroll
        for (int f = 0; f < 8; f++) {
            bf16x8 bh = *(const bf16x8*)(Bc + f * 512);
            bf16x8 bl = *(const bf16x8*)(Bc + 4096 + f * 512);
            acc[f] = __builtin_amdgcn_mfma_f32_16x16x32_bf16(ah, bh, acc[f], 0, 0, 0);
            acc[f] = __builtin_amdgcn_mfma_f32_16x16x32_bf16(al, bh, acc[f], 0, 0, 0);
            acc[f] = __builtin_amdgcn_mfma_f32_16x16x32_bf16(ah, bl, acc[f], 0, 0, 0);
        }
        a0 = n0;
        a1 = n1;
    }

    // epilogue: row = m0 + w*16 + lq*4 + j, col = f*16 + l16
#pragma unroll
    for (int j = 0; j < 4; j++) {
        int grow = m0 + w * 16 + lq * 4 + j;
        if (grow < M) {
            float scale = dinv[grow];
            int gb = 0;
            if (ADD_COND) gb = batch[grow];
#pragma unroll
            for (int f = 0; f < 8; f++) {
                int gcol = f * 16 + l16;
                float v = acc[f][j];
                if (ADD_COND) v += condW[gb * HID + gcol];
                C[(size_t)grow * HID + gcol] = v * scale;
            }
        }
    }
}

// ---------------------------------------------------------------------------
// gather aggregation: out[d] = bias + dinv[d] * (u[d] + sum_{e: dst=d} u[src])
// ---------------------------------------------------------------------------
__global__ __launch_bounds__(256)
void agg_gather(const float* __restrict__ u, const float* __restrict__ dinv,
                const int* __restrict__ row_start, const int* __restrict__ csr_src,
                const float* __restrict__ bias, float* __restrict__ out) {
    int node = blockIdx.x * 4 + (threadIdx.x >> 6);
    int lane = threadIdx.x & 63;
    if (node >= NN) return;
    int p = row_start[node], pend = row_start[node + 1];
    float2 acc = *(const float2*)&u[(size_t)node * HID + lane * 2];
    int s = (p < pend) ? csr_src[p] : 0;
    while (p < pend) {
        int sn = (p + 1 < pend) ? csr_src[p + 1] : 0;
        float2 v = *(const float2*)&u[(size_t)s * HID + lane * 2];
        acc.x += v.x;
        acc.y += v.y;
        s = sn;
        ++p;
    }
    float dd = dinv[node];
    float2 bb = *(const float2*)&bias[lane * 2];
    float2 o;
    o.x = fmaf(dd, acc.x, bb.x);
    o.y = fmaf(dd, acc.y, bb.y);
    *(float2*)&out[(size_t)node * HID + lane * 2] = o;
}

// ---------------------------------------------------------------------------
// logits[i] = relu(h[i]) @ W_out + b_out
// ---------------------------------------------------------------------------
__global__ void out_kernel(const float* __restrict__ h, const float* __restrict__ Wout,
                           const float* __restrict__ bout, float* __restrict__ logits) {
    int gid = blockIdx.x * blockDim.x + threadIdx.x;
    int node = gid >> 6;
    int lane = threadIdx.x & 63;
    if (node >= NN) return;
    const float* row = h + (size_t)node * HID;
    float v = fmaxf(row[lane], 0.f) * Wout[lane] +
              fmaxf(row[lane + 64], 0.f) * Wout[lane + 64];
#pragma unroll
    for (int o = 32; o; o >>= 1) v += __shfl_down(v, o);
    if (lane == 0) logits[node] = v + bout[0];
}

// ---------------------------------------------------------------------------
extern "C" void kernel_launch(void* const* d_in, const int* in_sizes, int n_in,
                              void* d_out, int out_size, void* d_ws, size_t ws_size,
                              hipStream_t stream) {
    const float* x     = (const float*)d_in[0];
    const int*   ei    = (const int*)d_in[1];
    const float* se    = (const float*)d_in[2];
    const int*   batch = (const int*)d_in[3];
    const float* W1    = (const float*)d_in[4];
    const float* b1    = (const float*)d_in[5];
    const float* W2    = (const float*)d_in[6];
    const float* b2    = (const float*)d_in[7];
    const float* Wout  = (const float*)d_in[8];
    const float* bout  = (const float*)d_in[9];
    float* logits = (float*)d_out;

    const int* srcp = ei;
    const int* dstp = ei + NE;

    // workspace carve (float offsets; 16B-aligned)
    float* ws       = (float*)d_ws;
    float* dinv     = ws;                        // 50176
    float* condW    = ws + 50176;                // 8192
    u16*   W1p      = (u16*)(ws + 58368);        // 24*8192 u16 = 98304 f
    u16*   W2p      = (u16*)(ws + 156672);       // 4*8192 u16 = 16384 f
    int*   counts   = (int*)(ws + 173056);       // 50176 (reused as cursor)
    int*   row_st   = (int*)(ws + 223232);       // 50176
    int*   csr_src  = (int*)(ws + 273408);       // 600000
    int*   bsum     = (int*)(ws + 873408);       // 256
    float* bufA     = ws + 873664;               // 6.4M
    float* bufB     = bufA + (size_t)NN * HID;   // 6.4M

    const int NB = (NN + 255) / 256;  // 196

    // degree + CSR build
    zero_counts<<<NB, 256, 0, stream>>>(counts);
    deg_count<<<(NE + 255) / 256, 256, 0, stream>>>(dstp, counts);
    deg_fin<<<NB, 256, 0, stream>>>(counts, dinv);
    pscan1<<<NB, 256, 0, stream>>>(counts, row_st, bsum);
    pscan2<<<1, 256, 0, stream>>>(bsum, NB);
    pscan3<<<NB, 256, 0, stream>>>(row_st, bsum, counts);
    csr_fill<<<(NE + 255) / 256, 256, 0, stream>>>(srcp, dstp, counts, csr_src);

    // weight prep
    cond_gemm<<<NG, 128, 0, stream>>>(se, W1, condW);
    wt_pack<<<(24 * 512 + 255) / 256, 256, 0, stream>>>(W1, W1p, INCH);
    wt_pack<<<(4 * 512 + 255) / 256, 256, 0, stream>>>(W2, W2p, HID);

    // layer 1: u1 = (x @ W1[:768] + condW[batch]) * dinv
    mfma_gemm<INCH, false, true><<<(NN + 63) / 64, 256, 0, stream>>>(
        x, W1p, bufA, condW, batch, dinv, NN);
    agg_gather<<<(NN + 3) / 4, 256, 0, stream>>>(bufA, dinv, row_st, csr_src, b1, bufB);

    // layer 2: u2 = (relu(h1) @ W2) * dinv
    mfma_gemm<HID, true, false><<<(NN + 63) / 64, 256, 0, stream>>>(
        bufB, W2p, bufA, nullptr, nullptr, dinv, NN);
    agg_gather<<<(NN + 3) / 4, 256, 0, stream>>>(bufA, dinv, row_st, csr_src, b2, bufB);

    // output head
    out_kernel<<<(NN * 64 + 255) / 256, 256, 0, stream>>>(bufB, Wout, bout, logits);
}

// Round 5
// 326.550 us; speedup vs baseline: 2.7092x; 1.0334x over previous
//
#include <hip/hip_runtime.h>
#include <math.h>

#define NN 50000
#define NE 600000
#define NG 64
#define INCH 768
#define HID 128

typedef __attribute__((ext_vector_type(8))) short bf16x8;
typedef __attribute__((ext_vector_type(4))) float f32x4;
typedef __attribute__((ext_vector_type(4))) unsigned int u32x4;
typedef unsigned short u16;
typedef unsigned int u32;
typedef unsigned long long u64;

__device__ __forceinline__ u16 f2bf(float v) {
    u32 u = __builtin_bit_cast(u32, v);
    u32 r = u + 0x7FFFu + ((u >> 16) & 1u);
    return (u16)(r >> 16);
}
__device__ __forceinline__ float bf2f(u16 h) {
    u32 u = ((u32)h) << 16;
    return __builtin_bit_cast(float, u);
}
__device__ __forceinline__ u32 cvtpk(float a, float b) {
    u32 r;
    asm("v_cvt_pk_bf16_f32 %0, %1, %2" : "=v"(r) : "v"(a), "v"(b));
    return r;
}

// ---------------------------------------------------------------------------
// degree counts
// ---------------------------------------------------------------------------
__global__ void deg_count(const int* __restrict__ dst, int* counts) {
    int e = blockIdx.x * blockDim.x + threadIdx.x;
    if (e < NE) atomicAdd(&counts[dst[e]], 1);
}

// ---------------------------------------------------------------------------
// CSR build (pscan1 also emits dinv = rsqrt(deg+1))
// ---------------------------------------------------------------------------
__global__ void pscan1(const int* __restrict__ counts, int* __restrict__ row_start,
                       int* __restrict__ bsum, float* __restrict__ dinv) {
    __shared__ int sm[256];
    int t = threadIdx.x;
    int i = blockIdx.x * 256 + t;
    int v = (i < NN) ? counts[i] : 0;
    if (i < NN) dinv[i] = rsqrtf((float)v + 1.0f);  // +1 self-loop
    sm[t] = v;
    __syncthreads();
#pragma unroll
    for (int off = 1; off < 256; off <<= 1) {
        int add = (t >= off) ? sm[t - off] : 0;
        __syncthreads();
        sm[t] += add;
        __syncthreads();
    }
    row_start[i] = sm[t] - v;
    if (t == 255) bsum[blockIdx.x] = sm[t];
}

__global__ void pscan2(int* bsum, int nb) {
    __shared__ int sm[256];
    int t = threadIdx.x;
    int v = (t < nb) ? bsum[t] : 0;
    sm[t] = v;
    __syncthreads();
#pragma unroll
    for (int off = 1; off < 256; off <<= 1) {
        int add = (t >= off) ? sm[t - off] : 0;
        __syncthreads();
        sm[t] += add;
        __syncthreads();
    }
    if (t < nb) bsum[t] = sm[t] - v;
}

__global__ void pscan3(int* __restrict__ row_start, const int* __restrict__ bsum,
                       int* __restrict__ cursor) {
    int i = blockIdx.x * 256 + threadIdx.x;
    int v = row_start[i] + bsum[blockIdx.x];
    row_start[i] = v;
    if (i < NN) cursor[i] = v;
}

__global__ void csr_fill(const int* __restrict__ src, const int* __restrict__ dst,
                         int* __restrict__ cursor, int* __restrict__ csr_src) {
    int e = blockIdx.x * blockDim.x + threadIdx.x;
    if (e < NE) {
        int pos = atomicAdd(&cursor[dst[e]], 1);
        csr_src[pos] = src[e];
    }
}

// ---------------------------------------------------------------------------
// condW[g][c] = substring_embed[g] @ W1[768: , c]
// ---------------------------------------------------------------------------
__global__ void cond_gemm(const float* __restrict__ SE,
                          const float* __restrict__ W1,
                          float* __restrict__ condW) {
    __shared__ float se[INCH];
    int g = blockIdx.x, t = threadIdx.x;
    for (int i = t; i < INCH; i += 128) se[i] = SE[g * INCH + i];
    __syncthreads();
    const float* Wb = W1 + (size_t)INCH * HID;
    float acc = 0.f;
    for (int k = 0; k < INCH; k++)
        acc = fmaf(se[k], Wb[(size_t)k * HID + t], acc);
    condW[g * HID + t] = acc;
}

// ---------------------------------------------------------------------------
// Pack W [K][128] fp32 into MFMA-fragment order, split hi/lo bf16:
// P[c][hl][f][lane][e]; lane l supplies col = f*16+(l&15), k = c*32+(l>>4)*8+e
// ---------------------------------------------------------------------------
__global__ void wt_pack(const float* __restrict__ W, u16* __restrict__ P, int K) {
    int tid = blockIdx.x * blockDim.x + threadIdx.x;
    int total = (K / 32) * 512;
    if (tid >= total) return;
    int l = tid & 63;
    int f = (tid >> 6) & 7;
    int c = tid >> 9;
    int n = f * 16 + (l & 15);
    int kb = c * 32 + ((l >> 4) & 3) * 8;
    u64 h0 = 0, h1 = 0, l0 = 0, l1 = 0;
#pragma unroll
    for (int e = 0; e < 8; e++) {
        float v = W[(size_t)(kb + e) * HID + n];
        u16 h = f2bf(v);
        u16 r = f2bf(v - bf2f(h));
        if (e < 4) { h0 |= (u64)h << (16 * e);       l0 |= (u64)r << (16 * e); }
        else       { h1 |= (u64)h << (16 * (e - 4)); l1 |= (u64)r << (16 * (e - 4)); }
    }
    size_t base = (size_t)c * 8192 + (size_t)f * 512 + l * 8;
    *(u64*)&P[base]          = h0;
    *(u64*)&P[base + 4]      = h1;
    *(u64*)&P[base + 4096]   = l0;
    *(u64*)&P[base + 4100]   = l1;
}

// ---------------------------------------------------------------------------
// u[M,128] = (op(A) @ W + cond) * dinv[row]
// Barrier-free split-bf16 MFMA, register-pipelined:
//   prefetch next-chunk bh[8] + A while computing; bl issued at loop top,
//   consumed 16 MFMAs later. Fully unrolled -> all static indexing.
// ---------------------------------------------------------------------------
template <int K, bool RELU_A, bool ADD_COND>
__global__ __launch_bounds__(256, 3)
void mfma_gemm(const float* __restrict__ A, const u16* __restrict__ P,
               float* __restrict__ C, const float* __restrict__ condW,
               const int* __restrict__ batch, const float* __restrict__ dinv,
               int M) {
    constexpr int NC = K / 32;
    const int t = threadIdx.x;
    const int w = t >> 6;
    const int l = t & 63;
    const int l16 = l & 15;
    const int lq = l >> 4;
    const int m0 = blockIdx.x * 64;
    const int arow = m0 + w * 16 + l16;
    const bool rowok = arow < M;
    const float* Ap = A + (size_t)(rowok ? arow : 0) * K + lq * 8;
    const u16* Pl = P + l * 8;

    f32x4 acc[8] = {};

    // prologue: A chunk0 + bh chunk0
    float4 a0 = make_float4(0.f, 0.f, 0.f, 0.f), a1 = a0;
    if (rowok) {
        a0 = *(const float4*)Ap;
        a1 = *(const float4*)(Ap + 4);
    }
    bf16x8 bhc[8];
#pragma unroll
    for (int f = 0; f < 8; f++) bhc[f] = *(const bf16x8*)(Pl + f * 512);

#pragma unroll
    for (int c = 0; c < NC; ++c) {
        const int cn = (c + 1 < NC) ? c + 1 : c;
        const u16* Bc = Pl + (size_t)c * 8192;
        const u16* Bn = Pl + (size_t)cn * 8192;

        // (1) current-chunk bl — used 16 MFMAs below
        bf16x8 bl[8];
#pragma unroll
        for (int f = 0; f < 8; f++) bl[f] = *(const bf16x8*)(Bc + 4096 + f * 512);
        // (2) next-chunk bh
        bf16x8 bhn[8];
#pragma unroll
        for (int f = 0; f < 8; f++) bhn[f] = *(const bf16x8*)(Bn + f * 512);
        // (3) next A
        float4 n0 = a0, n1 = a1;
        if (c + 1 < NC && rowok) {
            n0 = *(const float4*)(Ap + 32 * (c + 1));
            n1 = *(const float4*)(Ap + 32 * (c + 1) + 4);
        }

        // (4) RTNE hi/lo split of current A
        float4 b0 = a0, b1 = a1;
        if (RELU_A) {
            b0.x = fmaxf(b0.x, 0.f); b0.y = fmaxf(b0.y, 0.f);
            b0.z = fmaxf(b0.z, 0.f); b0.w = fmaxf(b0.w, 0.f);
            b1.x = fmaxf(b1.x, 0.f); b1.y = fmaxf(b1.y, 0.f);
            b1.z = fmaxf(b1.z, 0.f); b1.w = fmaxf(b1.w, 0.f);
        }
        u32 h0 = cvtpk(b0.x, b0.y), h1 = cvtpk(b0.z, b0.w);
        u32 h2 = cvtpk(b1.x, b1.y), h3 = cvtpk(b1.z, b1.w);
        float r0 = b0.x - __builtin_bit_cast(float, h0 << 16);
        float r1 = b0.y - __builtin_bit_cast(float, h0 & 0xFFFF0000u);
        float r2 = b0.z - __builtin_bit_cast(float, h1 << 16);
        float r3 = b0.w - __builtin_bit_cast(float, h1 & 0xFFFF0000u);
        float r4 = b1.x - __builtin_bit_cast(float, h2 << 16);
        float r5 = b1.y - __builtin_bit_cast(float, h2 & 0xFFFF0000u);
        float r6 = b1.z - __builtin_bit_cast(float, h3 << 16);
        float r7 = b1.w - __builtin_bit_cast(float, h3 & 0xFFFF0000u);
        u32 e0 = cvtpk(r0, r1), e1 = cvtpk(r2, r3);
        u32 e2 = cvtpk(r4, r5), e3 = cvtpk(r6, r7);
        bf16x8 ah = __builtin_bit_cast(bf16x8, (u32x4){h0, h1, h2, h3});
        bf16x8 al = __builtin_bit_cast(bf16x8, (u32x4){e0, e1, e2, e3});

        // (5-7) MFMAs: bh terms first, bl term last (max load->use distance)
#pragma unroll
        for (int f = 0; f < 8; f++)
            acc[f] = __builtin_amdgcn_mfma_f32_16x16x32_bf16(ah, bhc[f], acc[f], 0, 0, 0);
#pragma unroll
        for (int f = 0; f < 8; f++)
            acc[f] = __builtin_amdgcn_mfma_f32_16x16x32_bf16(al, bhc[f], acc[f], 0, 0, 0);
#pragma unroll
        for (int f = 0; f < 8; f++)
            acc[f] = __builtin_amdgcn_mfma_f32_16x16x32_bf16(ah, bl[f], acc[f], 0, 0, 0);

        // (8) rotate (SSA renames under full unroll)
        a0 = n0; a1 = n1;
#pragma unroll
        for (int f = 0; f < 8; f++) bhc[f] = bhn[f];
    }

    // epilogue: row = m0 + w*16 + lq*4 + j, col = f*16 + l16
#pragma unroll
    for (int j = 0; j < 4; j++) {
        int grow = m0 + w * 16 + lq * 4 + j;
        if (grow < M) {
            float scale = dinv[grow];
            int gb = 0;
            if (ADD_COND) gb = batch[grow];
#pragma unroll
            for (int f = 0; f < 8; f++) {
                int gcol = f * 16 + l16;
                float v = acc[f][j];
                if (ADD_COND) v += condW[gb * HID + gcol];
                C[(size_t)grow * HID + gcol] = v * scale;
            }
        }
    }
}

// ---------------------------------------------------------------------------
// gather aggregation: o[d] = bias + dinv[d]*(u[d] + sum u[src])
// FUSE_OUT: logits[d] = relu(o) . Wout + bout  (no h2 materialization)
// ---------------------------------------------------------------------------
template <bool FUSE_OUT>
__global__ __launch_bounds__(256)
void agg_gather(const float* __restrict__ u, const float* __restrict__ dinv,
                const int* __restrict__ row_start, const int* __restrict__ csr_src,
                const float* __restrict__ bias, float* __restrict__ out,
                const float* __restrict__ Wout, const float* __restrict__ bout,
                float* __restrict__ logits) {
    int node = blockIdx.x * 4 + (threadIdx.x >> 6);
    int lane = threadIdx.x & 63;
    if (node >= NN) return;
    int p = row_start[node], pend = row_start[node + 1];
    float2 acc = *(const float2*)&u[(size_t)node * HID + lane * 2];
    int s = (p < pend) ? csr_src[p] : 0;
    while (p < pend) {
        int sn = (p + 1 < pend) ? csr_src[p + 1] : 0;
        float2 v = *(const float2*)&u[(size_t)s * HID + lane * 2];
        acc.x += v.x;
        acc.y += v.y;
        s = sn;
        ++p;
    }
    float dd = dinv[node];
    float2 bb = *(const float2*)&bias[lane * 2];
    float ox = fmaf(dd, acc.x, bb.x);
    float oy = fmaf(dd, acc.y, bb.y);
    if (FUSE_OUT) {
        float2 wv = *(const float2*)&Wout[lane * 2];
        float v = fmaxf(ox, 0.f) * wv.x + fmaxf(oy, 0.f) * wv.y;
#pragma unroll
        for (int o = 32; o; o >>= 1) v += __shfl_down(v, o);
        if (lane == 0) logits[node] = v + bout[0];
    } else {
        float2 o;
        o.x = ox;
        o.y = oy;
        *(float2*)&out[(size_t)node * HID + lane * 2] = o;
    }
}

// ---------------------------------------------------------------------------
extern "C" void kernel_launch(void* const* d_in, const int* in_sizes, int n_in,
                              void* d_out, int out_size, void* d_ws, size_t ws_size,
                              hipStream_t stream) {
    const float* x     = (const float*)d_in[0];
    const int*   ei    = (const int*)d_in[1];
    const float* se    = (const float*)d_in[2];
    const int*   batch = (const int*)d_in[3];
    const float* W1    = (const float*)d_in[4];
    const float* b1    = (const float*)d_in[5];
    const float* W2    = (const float*)d_in[6];
    const float* b2    = (const float*)d_in[7];
    const float* Wout  = (const float*)d_in[8];
    const float* bout  = (const float*)d_in[9];
    float* logits = (float*)d_out;

    const int* srcp = ei;
    const int* dstp = ei + NE;

    // workspace carve (float offsets; 16B-aligned)
    float* ws       = (float*)d_ws;
    float* dinv     = ws;                        // 50176
    float* condW    = ws + 50176;                // 8192
    u16*   W1p      = (u16*)(ws + 58368);        // 98304 f
    u16*   W2p      = (u16*)(ws + 156672);       // 16384 f
    int*   counts   = (int*)(ws + 173056);       // 50176 (reused as cursor)
    int*   row_st   = (int*)(ws + 223232);       // 50176
    int*   csr_src  = (int*)(ws + 273408);       // 600000
    int*   bsum     = (int*)(ws + 873408);       // 256
    float* bufA     = ws + 873664;               // 6.4M
    float* bufB     = bufA + (size_t)NN * HID;   // 6.4M

    const int NB = (NN + 255) / 256;  // 196

    // degree + CSR build
    hipMemsetAsync(counts, 0, NN * sizeof(int), stream);
    deg_count<<<(NE + 255) / 256, 256, 0, stream>>>(dstp, counts);
    pscan1<<<NB, 256, 0, stream>>>(counts, row_st, bsum, dinv);
    pscan2<<<1, 256, 0, stream>>>(bsum, NB);
    pscan3<<<NB, 256, 0, stream>>>(row_st, bsum, counts);
    csr_fill<<<(NE + 255) / 256, 256, 0, stream>>>(srcp, dstp, counts, csr_src);

    // weight prep
    cond_gemm<<<NG, 128, 0, stream>>>(se, W1, condW);
    wt_pack<<<(24 * 512 + 255) / 256, 256, 0, stream>>>(W1, W1p, INCH);
    wt_pack<<<(4 * 512 + 255) / 256, 256, 0, stream>>>(W2, W2p, HID);

    // layer 1
    mfma_gemm<INCH, false, true><<<(NN + 63) / 64, 256, 0, stream>>>(
        x, W1p, bufA, condW, batch, dinv, NN);
    agg_gather<false><<<(NN + 3) / 4, 256, 0, stream>>>(
        bufA, dinv, row_st, csr_src, b1, bufB, nullptr, nullptr, nullptr);

    // layer 2 (+ fused output head)
    mfma_gemm<HID, true, false><<<(NN + 63) / 64, 256, 0, stream>>>(
        bufB, W2p, bufA, nullptr, nullptr, dinv, NN);
    agg_gather<true><<<(NN + 3) / 4, 256, 0, stream>>>(
        bufA, dinv, row_st, csr_src, b2, nullptr, Wout, bout, logits);
}

// Round 6
// 286.913 us; speedup vs baseline: 3.0834x; 1.1381x over previous
//
#include <hip/hip_runtime.h>
#include <math.h>

#define NN 50000
#define NE 600000
#define NG 64
#define INCH 768
#define HID 128

typedef __attribute__((ext_vector_type(8))) short bf16x8;
typedef __attribute__((ext_vector_type(4))) float f32x4;
typedef __attribute__((ext_vector_type(4))) unsigned int u32x4;
typedef unsigned short u16;
typedef unsigned int u32;
typedef unsigned long long u64;

__device__ __forceinline__ u16 f2bf(float v) {
    u32 u = __builtin_bit_cast(u32, v);
    u32 r = u + 0x7FFFu + ((u >> 16) & 1u);
    return (u16)(r >> 16);
}
__device__ __forceinline__ float bf2f(u16 h) {
    u32 u = ((u32)h) << 16;
    return __builtin_bit_cast(float, u);
}
__device__ __forceinline__ u32 cvtpk(float a, float b) {
    u32 r;
    asm("v_cvt_pk_bf16_f32 %0, %1, %2" : "=v"(r) : "v"(a), "v"(b));
    return r;
}

struct SplitA { bf16x8 h, l; };

// RTNE hi/lo split of 8 floats (optionally relu'd)
template <bool RELU>
__device__ __forceinline__ SplitA splitA(float4 b0, float4 b1) {
    if (RELU) {
        b0.x = fmaxf(b0.x, 0.f); b0.y = fmaxf(b0.y, 0.f);
        b0.z = fmaxf(b0.z, 0.f); b0.w = fmaxf(b0.w, 0.f);
        b1.x = fmaxf(b1.x, 0.f); b1.y = fmaxf(b1.y, 0.f);
        b1.z = fmaxf(b1.z, 0.f); b1.w = fmaxf(b1.w, 0.f);
    }
    u32 h0 = cvtpk(b0.x, b0.y), h1 = cvtpk(b0.z, b0.w);
    u32 h2 = cvtpk(b1.x, b1.y), h3 = cvtpk(b1.z, b1.w);
    float r0 = b0.x - __builtin_bit_cast(float, h0 << 16);
    float r1 = b0.y - __builtin_bit_cast(float, h0 & 0xFFFF0000u);
    float r2 = b0.z - __builtin_bit_cast(float, h1 << 16);
    float r3 = b0.w - __builtin_bit_cast(float, h1 & 0xFFFF0000u);
    float r4 = b1.x - __builtin_bit_cast(float, h2 << 16);
    float r5 = b1.y - __builtin_bit_cast(float, h2 & 0xFFFF0000u);
    float r6 = b1.z - __builtin_bit_cast(float, h3 << 16);
    float r7 = b1.w - __builtin_bit_cast(float, h3 & 0xFFFF0000u);
    u32 e0 = cvtpk(r0, r1), e1 = cvtpk(r2, r3);
    u32 e2 = cvtpk(r4, r5), e3 = cvtpk(r6, r7);
    SplitA s;
    s.h = __builtin_bit_cast(bf16x8, (u32x4){h0, h1, h2, h3});
    s.l = __builtin_bit_cast(bf16x8, (u32x4){e0, e1, e2, e3});
    return s;
}

// ---------------------------------------------------------------------------
// degree counts
// ---------------------------------------------------------------------------
__global__ void deg_count(const int* __restrict__ dst, int* counts) {
    int e = blockIdx.x * blockDim.x + threadIdx.x;
    if (e < NE) atomicAdd(&counts[dst[e]], 1);
}

// ---------------------------------------------------------------------------
// CSR build (pscan1 also emits dinv = rsqrt(deg+1))
// ---------------------------------------------------------------------------
__global__ void pscan1(const int* __restrict__ counts, int* __restrict__ row_start,
                       int* __restrict__ bsum, float* __restrict__ dinv) {
    __shared__ int sm[256];
    int t = threadIdx.x;
    int i = blockIdx.x * 256 + t;
    int v = (i < NN) ? counts[i] : 0;
    if (i < NN) dinv[i] = rsqrtf((float)v + 1.0f);  // +1 self-loop
    sm[t] = v;
    __syncthreads();
#pragma unroll
    for (int off = 1; off < 256; off <<= 1) {
        int add = (t >= off) ? sm[t - off] : 0;
        __syncthreads();
        sm[t] += add;
        __syncthreads();
    }
    row_start[i] = sm[t] - v;
    if (t == 255) bsum[blockIdx.x] = sm[t];
}

__global__ void pscan2(int* bsum, int nb) {
    __shared__ int sm[256];
    int t = threadIdx.x;
    int v = (t < nb) ? bsum[t] : 0;
    sm[t] = v;
    __syncthreads();
#pragma unroll
    for (int off = 1; off < 256; off <<= 1) {
        int add = (t >= off) ? sm[t - off] : 0;
        __syncthreads();
        sm[t] += add;
        __syncthreads();
    }
    if (t < nb) bsum[t] = sm[t] - v;
}

__global__ void pscan3(int* __restrict__ row_start, const int* __restrict__ bsum,
                       int* __restrict__ cursor) {
    int i = blockIdx.x * 256 + threadIdx.x;
    int v = row_start[i] + bsum[blockIdx.x];
    row_start[i] = v;
    if (i < NN) cursor[i] = v;
}

__global__ void csr_fill(const int* __restrict__ src, const int* __restrict__ dst,
                         int* __restrict__ cursor, int* __restrict__ csr_src) {
    int e = blockIdx.x * blockDim.x + threadIdx.x;
    if (e < NE) {
        int pos = atomicAdd(&cursor[dst[e]], 1);
        csr_src[pos] = src[e];
    }
}

// ---------------------------------------------------------------------------
// condW[g][c] = substring_embed[g] @ W1[768: , c]
// ---------------------------------------------------------------------------
__global__ void cond_gemm(const float* __restrict__ SE,
                          const float* __restrict__ W1,
                          float* __restrict__ condW) {
    __shared__ float se[INCH];
    int g = blockIdx.x, t = threadIdx.x;
    for (int i = t; i < INCH; i += 128) se[i] = SE[g * INCH + i];
    __syncthreads();
    const float* Wb = W1 + (size_t)INCH * HID;
    float acc = 0.f;
    for (int k = 0; k < INCH; k++)
        acc = fmaf(se[k], Wb[(size_t)k * HID + t], acc);
    condW[g * HID + t] = acc;
}

// ---------------------------------------------------------------------------
// Pack W [K][128] fp32 into MFMA-fragment order, split hi/lo bf16:
// P[c][hl][f][lane][e]; lane l supplies col = f*16+(l&15), k = c*32+(l>>4)*8+e
// chunk stride 16KB: bh at [0,8K), bl at [8K,16K)
// ---------------------------------------------------------------------------
__global__ void wt_pack(const float* __restrict__ W, u16* __restrict__ P, int K) {
    int tid = blockIdx.x * blockDim.x + threadIdx.x;
    int total = (K / 32) * 512;
    if (tid >= total) return;
    int l = tid & 63;
    int f = (tid >> 6) & 7;
    int c = tid >> 9;
    int n = f * 16 + (l & 15);
    int kb = c * 32 + ((l >> 4) & 3) * 8;
    u64 h0 = 0, h1 = 0, l0 = 0, l1 = 0;
#pragma unroll
    for (int e = 0; e < 8; e++) {
        float v = W[(size_t)(kb + e) * HID + n];
        u16 h = f2bf(v);
        u16 r = f2bf(v - bf2f(h));
        if (e < 4) { h0 |= (u64)h << (16 * e);       l0 |= (u64)r << (16 * e); }
        else       { h1 |= (u64)h << (16 * (e - 4)); l1 |= (u64)r << (16 * (e - 4)); }
    }
    size_t base = (size_t)c * 8192 + (size_t)f * 512 + l * 8;
    *(u64*)&P[base]          = h0;
    *(u64*)&P[base + 4]      = h1;
    *(u64*)&P[base + 4096]   = l0;
    *(u64*)&P[base + 4100]   = l1;
}

// ---------------------------------------------------------------------------
// u[M,128] = (op(A) @ W + cond) * dinv[row]
// 4 waves x 32 rows = 128 rows/block. Packed B chunk (16KB) staged to LDS
// (reg-staged, double-buffered, one barrier/chunk); A streamed to registers.
// ---------------------------------------------------------------------------
template <int K, bool RELU_A, bool ADD_COND>
__global__ __launch_bounds__(256, 2)
void mfma_gemm(const float* __restrict__ A, const u16* __restrict__ P,
               float* __restrict__ C, const float* __restrict__ condW,
               const int* __restrict__ batch, const float* __restrict__ dinv,
               int M) {
    constexpr int NC = K / 32;
    __shared__ u16 Bs[2][8192];   // [buf][16KB chunk]
    const int t = threadIdx.x;
    const int w = t >> 6;
    const int l = t & 63;
    const int l16 = l & 15;
    const int lq = l >> 4;
    const int m0 = blockIdx.x * 128;

    // rows: set s -> m0 + w*32 + s*16 + l16
    const int r0 = m0 + w * 32 + l16;
    const int r1 = r0 + 16;
    const bool ok0 = r0 < M, ok1 = r1 < M;
    const float* Ap0 = A + (size_t)(ok0 ? r0 : 0) * K + lq * 8;
    const float* Ap1 = A + (size_t)(ok1 ? r1 : 0) * K + lq * 8;
    const char* Pb = (const char*)P + t * 16;   // staging base for this thread

    f32x4 acc[2][8] = {};

    // ---- prologue: stage chunk 0, load A chunk 0 ----
    float4 a00 = make_float4(0.f, 0.f, 0.f, 0.f), a01 = a00, a10 = a00, a11 = a00;
    {
        float4 g0 = *(const float4*)(Pb);
        float4 g1 = *(const float4*)(Pb + 4096);
        float4 g2 = *(const float4*)(Pb + 8192);
        float4 g3 = *(const float4*)(Pb + 12288);
        if (ok0) { a00 = *(const float4*)Ap0; a01 = *(const float4*)(Ap0 + 4); }
        if (ok1) { a10 = *(const float4*)Ap1; a11 = *(const float4*)(Ap1 + 4); }
        *(float4*)&Bs[0][t * 8]        = g0;
        *(float4*)&Bs[0][2048 + t * 8] = g1;
        *(float4*)&Bs[0][4096 + t * 8] = g2;
        *(float4*)&Bs[0][6144 + t * 8] = g3;
    }
    __syncthreads();

    for (int c = 0; c < NC; ++c) {
        const int cur = c & 1, nxt = cur ^ 1;
        const bool hasNext = (c + 1 < NC);

        // (1) issue next-chunk staging loads + next A (hidden under compute)
        float4 g0, g1, g2, g3, n00 = a00, n01 = a01, n10 = a10, n11 = a11;
        if (hasNext) {
            const char* src = Pb + (size_t)(c + 1) * 16384;
            g0 = *(const float4*)(src);
            g1 = *(const float4*)(src + 4096);
            g2 = *(const float4*)(src + 8192);
            g3 = *(const float4*)(src + 12288);
            if (ok0) {
                n00 = *(const float4*)(Ap0 + 32 * (c + 1));
                n01 = *(const float4*)(Ap0 + 32 * (c + 1) + 4);
            }
            if (ok1) {
                n10 = *(const float4*)(Ap1 + 32 * (c + 1));
                n11 = *(const float4*)(Ap1 + 32 * (c + 1) + 4);
            }
        }

        // (2) B fragments from LDS
        bf16x8 bh[8], bl[8];
#pragma unroll
        for (int f = 0; f < 8; f++)
            bh[f] = *(const bf16x8*)&Bs[cur][f * 512 + l * 8];
#pragma unroll
        for (int f = 0; f < 8; f++)
            bl[f] = *(const bf16x8*)&Bs[cur][4096 + f * 512 + l * 8];

        // (3) split current A
        SplitA s0 = splitA<RELU_A>(a00, a01);
        SplitA s1 = splitA<RELU_A>(a10, a11);

        // (4) MFMAs (per-acc order: ah*bh, al*bh, ah*bl — bitwise stable)
#pragma unroll
        for (int f = 0; f < 8; f++) {
            acc[0][f] = __builtin_amdgcn_mfma_f32_16x16x32_bf16(s0.h, bh[f], acc[0][f], 0, 0, 0);
            acc[1][f] = __builtin_amdgcn_mfma_f32_16x16x32_bf16(s1.h, bh[f], acc[1][f], 0, 0, 0);
        }
#pragma unroll
        for (int f = 0; f < 8; f++) {
            acc[0][f] = __builtin_amdgcn_mfma_f32_16x16x32_bf16(s0.l, bh[f], acc[0][f], 0, 0, 0);
            acc[1][f] = __builtin_amdgcn_mfma_f32_16x16x32_bf16(s1.l, bh[f], acc[1][f], 0, 0, 0);
        }
#pragma unroll
        for (int f = 0; f < 8; f++) {
            acc[0][f] = __builtin_amdgcn_mfma_f32_16x16x32_bf16(s0.h, bl[f], acc[0][f], 0, 0, 0);
            acc[1][f] = __builtin_amdgcn_mfma_f32_16x16x32_bf16(s1.h, bl[f], acc[1][f], 0, 0, 0);
        }

        // (5) write next chunk into other buffer, rotate A
        if (hasNext) {
            *(float4*)&Bs[nxt][t * 8]        = g0;
            *(float4*)&Bs[nxt][2048 + t * 8] = g1;
            *(float4*)&Bs[nxt][4096 + t * 8] = g2;
            *(float4*)&Bs[nxt][6144 + t * 8] = g3;
            a00 = n00; a01 = n01; a10 = n10; a11 = n11;
        }
        __syncthreads();
    }

    // epilogue: row = m0 + w*32 + s*16 + lq*4 + j, col = f*16 + l16
#pragma unroll
    for (int s = 0; s < 2; s++) {
#pragma unroll
        for (int j = 0; j < 4; j++) {
            int grow = m0 + w * 32 + s * 16 + lq * 4 + j;
            if (grow < M) {
                float scale = dinv[grow];
                int gb = 0;
                if (ADD_COND) gb = batch[grow];
#pragma unroll
                for (int f = 0; f < 8; f++) {
                    int gcol = f * 16 + l16;
                    float v = acc[s][f][j];
                    if (ADD_COND) v += condW[gb * HID + gcol];
                    C[(size_t)grow * HID + gcol] = v * scale;
                }
            }
        }
    }
}

// ---------------------------------------------------------------------------
// gather aggregation: o[d] = bias + dinv[d]*(u[d] + sum u[src])
// FUSE_OUT: logits[d] = relu(o) . Wout + bout
// ---------------------------------------------------------------------------
template <bool FUSE_OUT>
__global__ __launch_bounds__(256)
void agg_gather(const float* __restrict__ u, const float* __restrict__ dinv,
                const int* __restrict__ row_start, const int* __restrict__ csr_src,
                const float* __restrict__ bias, float* __restrict__ out,
                const float* __restrict__ Wout, const float* __restrict__ bout,
                float* __restrict__ logits) {
    int node = blockIdx.x * 4 + (threadIdx.x >> 6);
    int lane = threadIdx.x & 63;
    if (node >= NN) return;
    int p = row_start[node], pend = row_start[node + 1];
    float2 acc = *(const float2*)&u[(size_t)node * HID + lane * 2];
    int s = (p < pend) ? csr_src[p] : 0;
    while (p < pend) {
        int sn = (p + 1 < pend) ? csr_src[p + 1] : 0;
        float2 v = *(const float2*)&u[(size_t)s * HID + lane * 2];
        acc.x += v.x;
        acc.y += v.y;
        s = sn;
        ++p;
    }
    float dd = dinv[node];
    float2 bb = *(const float2*)&bias[lane * 2];
    float ox = fmaf(dd, acc.x, bb.x);
    float oy = fmaf(dd, acc.y, bb.y);
    if (FUSE_OUT) {
        float2 wv = *(const float2*)&Wout[lane * 2];
        float v = fmaxf(ox, 0.f) * wv.x + fmaxf(oy, 0.f) * wv.y;
#pragma unroll
        for (int o = 32; o; o >>= 1) v += __shfl_down(v, o);
        if (lane == 0) logits[node] = v + bout[0];
    } else {
        float2 o;
        o.x = ox;
        o.y = oy;
        *(float2*)&out[(size_t)node * HID + lane * 2] = o;
    }
}

// ---------------------------------------------------------------------------
extern "C" void kernel_launch(void* const* d_in, const int* in_sizes, int n_in,
                              void* d_out, int out_size, void* d_ws, size_t ws_size,
                              hipStream_t stream) {
    const float* x     = (const float*)d_in[0];
    const int*   ei    = (const int*)d_in[1];
    const float* se    = (const float*)d_in[2];
    const int*   batch = (const int*)d_in[3];
    const float* W1    = (const float*)d_in[4];
    const float* b1    = (const float*)d_in[5];
    const float* W2    = (const float*)d_in[6];
    const float* b2    = (const float*)d_in[7];
    const float* Wout  = (const float*)d_in[8];
    const float* bout  = (const float*)d_in[9];
    float* logits = (float*)d_out;

    const int* srcp = ei;
    const int* dstp = ei + NE;

    // workspace carve (float offsets; 16B-aligned)
    float* ws       = (float*)d_ws;
    float* dinv     = ws;                        // 50176
    float* condW    = ws + 50176;                // 8192
    u16*   W1p      = (u16*)(ws + 58368);        // 98304 f
    u16*   W2p      = (u16*)(ws + 156672);       // 16384 f
    int*   counts   = (int*)(ws + 173056);       // 50176 (reused as cursor)
    int*   row_st   = (int*)(ws + 223232);       // 50176
    int*   csr_src  = (int*)(ws + 273408);       // 600000
    int*   bsum     = (int*)(ws + 873408);       // 256
    float* bufA     = ws + 873664;               // 6.4M
    float* bufB     = bufA + (size_t)NN * HID;   // 6.4M

    const int NB = (NN + 255) / 256;  // 196

    // degree + CSR build
    hipMemsetAsync(counts, 0, NN * sizeof(int), stream);
    deg_count<<<(NE + 255) / 256, 256, 0, stream>>>(dstp, counts);
    pscan1<<<NB, 256, 0, stream>>>(counts, row_st, bsum, dinv);
    pscan2<<<1, 256, 0, stream>>>(bsum, NB);
    pscan3<<<NB, 256, 0, stream>>>(row_st, bsum, counts);
    csr_fill<<<(NE + 255) / 256, 256, 0, stream>>>(srcp, dstp, counts, csr_src);

    // weight prep
    cond_gemm<<<NG, 128, 0, stream>>>(se, W1, condW);
    wt_pack<<<(24 * 512 + 255) / 256, 256, 0, stream>>>(W1, W1p, INCH);
    wt_pack<<<(4 * 512 + 255) / 256, 256, 0, stream>>>(W2, W2p, HID);

    // layer 1
    mfma_gemm<INCH, false, true><<<(NN + 127) / 128, 256, 0, stream>>>(
        x, W1p, bufA, condW, batch, dinv, NN);
    agg_gather<false><<<(NN + 3) / 4, 256, 0, stream>>>(
        bufA, dinv, row_st, csr_src, b1, bufB, nullptr, nullptr, nullptr);

    // layer 2 (+ fused output head)
    mfma_gemm<HID, true, false><<<(NN + 127) / 128, 256, 0, stream>>>(
        bufB, W2p, bufA, nullptr, nullptr, dinv, NN);
    agg_gather<true><<<(NN + 3) / 4, 256, 0, stream>>>(
        bufA, dinv, row_st, csr_src, b2, nullptr, Wout, bout, logits);
}

// Round 7
// 262.908 us; speedup vs baseline: 3.3650x; 1.0913x over previous
//
#include <hip/hip_runtime.h>
#include <math.h>

#define NN 50000
#define NNP 50176            // padded rows (block tail writes unguarded)
#define NE 600000
#define NG 64
#define INCH 768
#define HID 128

typedef __attribute__((ext_vector_type(8))) short bf16x8;
typedef __attribute__((ext_vector_type(4))) float f32x4;
typedef __attribute__((ext_vector_type(4))) unsigned int u32x4;
typedef unsigned short u16;
typedef unsigned int u32;
typedef unsigned long long u64;

__device__ __forceinline__ u16 f2bf(float v) {
    u32 u = __builtin_bit_cast(u32, v);
    u32 r = u + 0x7FFFu + ((u >> 16) & 1u);
    return (u16)(r >> 16);
}
__device__ __forceinline__ float bf2f(u16 h) {
    u32 u = ((u32)h) << 16;
    return __builtin_bit_cast(float, u);
}
__device__ __forceinline__ u32 cvtpk(float a, float b) {
    u32 r;
    asm("v_cvt_pk_bf16_f32 %0, %1, %2" : "=v"(r) : "v"(a), "v"(b));
    return r;
}

struct SplitA { bf16x8 h, l; };

template <bool RELU>
__device__ __forceinline__ SplitA splitA(float4 b0, float4 b1) {
    if (RELU) {
        b0.x = fmaxf(b0.x, 0.f); b0.y = fmaxf(b0.y, 0.f);
        b0.z = fmaxf(b0.z, 0.f); b0.w = fmaxf(b0.w, 0.f);
        b1.x = fmaxf(b1.x, 0.f); b1.y = fmaxf(b1.y, 0.f);
        b1.z = fmaxf(b1.z, 0.f); b1.w = fmaxf(b1.w, 0.f);
    }
    u32 h0 = cvtpk(b0.x, b0.y), h1 = cvtpk(b0.z, b0.w);
    u32 h2 = cvtpk(b1.x, b1.y), h3 = cvtpk(b1.z, b1.w);
    float r0 = b0.x - __builtin_bit_cast(float, h0 << 16);
    float r1 = b0.y - __builtin_bit_cast(float, h0 & 0xFFFF0000u);
    float r2 = b0.z - __builtin_bit_cast(float, h1 << 16);
    float r3 = b0.w - __builtin_bit_cast(float, h1 & 0xFFFF0000u);
    float r4 = b1.x - __builtin_bit_cast(float, h2 << 16);
    float r5 = b1.y - __builtin_bit_cast(float, h2 & 0xFFFF0000u);
    float r6 = b1.z - __builtin_bit_cast(float, h3 << 16);
    float r7 = b1.w - __builtin_bit_cast(float, h3 & 0xFFFF0000u);
    u32 e0 = cvtpk(r0, r1), e1 = cvtpk(r2, r3);
    u32 e2 = cvtpk(r4, r5), e3 = cvtpk(r6, r7);
    SplitA s;
    s.h = __builtin_bit_cast(bf16x8, (u32x4){h0, h1, h2, h3});
    s.l = __builtin_bit_cast(bf16x8, (u32x4){e0, e1, e2, e3});
    return s;
}

// ---------------------------------------------------------------------------
__global__ void deg_count(const int* __restrict__ dst, int* counts) {
    int e = blockIdx.x * blockDim.x + threadIdx.x;
    if (e < NE) atomicAdd(&counts[dst[e]], 1);
}

// ---------------------------------------------------------------------------
// CSR build (pscan1 also emits dinv = rsqrt(deg+1))
// ---------------------------------------------------------------------------
__global__ void pscan1(const int* __restrict__ counts, int* __restrict__ row_start,
                       int* __restrict__ bsum, float* __restrict__ dinv) {
    __shared__ int sm[256];
    int t = threadIdx.x;
    int i = blockIdx.x * 256 + t;
    int v = (i < NN) ? counts[i] : 0;
    if (i < NN) dinv[i] = rsqrtf((float)v + 1.0f);
    sm[t] = v;
    __syncthreads();
#pragma unroll
    for (int off = 1; off < 256; off <<= 1) {
        int add = (t >= off) ? sm[t - off] : 0;
        __syncthreads();
        sm[t] += add;
        __syncthreads();
    }
    row_start[i] = sm[t] - v;
    if (t == 255) bsum[blockIdx.x] = sm[t];
}

__global__ void pscan2(int* bsum, int nb) {
    __shared__ int sm[256];
    int t = threadIdx.x;
    int v = (t < nb) ? bsum[t] : 0;
    sm[t] = v;
    __syncthreads();
#pragma unroll
    for (int off = 1; off < 256; off <<= 1) {
        int add = (t >= off) ? sm[t - off] : 0;
        __syncthreads();
        sm[t] += add;
        __syncthreads();
    }
    if (t < nb) bsum[t] = sm[t] - v;
}

__global__ void pscan3(int* __restrict__ row_start, const int* __restrict__ bsum,
                       int* __restrict__ cursor) {
    int i = blockIdx.x * 256 + threadIdx.x;
    int v = row_start[i] + bsum[blockIdx.x];
    row_start[i] = v;
    if (i < NN) cursor[i] = v;
}

__global__ void csr_fill(const int* __restrict__ src, const int* __restrict__ dst,
                         int* __restrict__ cursor, int* __restrict__ csr_src) {
    int e = blockIdx.x * blockDim.x + threadIdx.x;
    if (e < NE) {
        int pos = atomicAdd(&cursor[dst[e]], 1);
        csr_src[pos] = src[e];
    }
}

// ---------------------------------------------------------------------------
// condW[g][c] = substring_embed[g] @ W1[768: , c]  (512 thr, 4-way K split)
// ---------------------------------------------------------------------------
__global__ __launch_bounds__(512)
void cond_gemm(const float* __restrict__ SE, const float* __restrict__ W1,
               float* __restrict__ condW) {
    __shared__ float se[INCH];
    __shared__ float part[4][HID];
    int g = blockIdx.x, t = threadIdx.x;
    for (int i = t; i < INCH; i += 512) se[i] = SE[g * INCH + i];
    __syncthreads();
    int col = t & 127, ks = t >> 7;          // ks = 0..3
    const float* Wb = W1 + (size_t)INCH * HID;
    float acc = 0.f;
    for (int k = ks * 192; k < ks * 192 + 192; k++)
        acc = fmaf(se[k], Wb[(size_t)k * HID + col], acc);
    part[ks][col] = acc;
    __syncthreads();
    if (t < HID)
        condW[g * HID + t] = part[0][t] + part[1][t] + part[2][t] + part[3][t];
}

// ---------------------------------------------------------------------------
// Pack W [K][128] fp32 into MFMA fragment order, hi/lo bf16
// ---------------------------------------------------------------------------
__global__ void wt_pack(const float* __restrict__ W, u16* __restrict__ P, int K) {
    int tid = blockIdx.x * blockDim.x + threadIdx.x;
    int total = (K / 32) * 512;
    if (tid >= total) return;
    int l = tid & 63;
    int f = (tid >> 6) & 7;
    int c = tid >> 9;
    int n = f * 16 + (l & 15);
    int kb = c * 32 + ((l >> 4) & 3) * 8;
    u64 h0 = 0, h1 = 0, l0 = 0, l1 = 0;
#pragma unroll
    for (int e = 0; e < 8; e++) {
        float v = W[(size_t)(kb + e) * HID + n];
        u16 h = f2bf(v);
        u16 r = f2bf(v - bf2f(h));
        if (e < 4) { h0 |= (u64)h << (16 * e);       l0 |= (u64)r << (16 * e); }
        else       { h1 |= (u64)h << (16 * (e - 4)); l1 |= (u64)r << (16 * (e - 4)); }
    }
    size_t base = (size_t)c * 8192 + (size_t)f * 512 + l * 8;
    *(u64*)&P[base]          = h0;
    *(u64*)&P[base + 4]      = h1;
    *(u64*)&P[base + 4096]   = l0;
    *(u64*)&P[base + 4100]   = l1;
}

// ---------------------------------------------------------------------------
// ubf[M,128] (bf16) = (op(A) @ W + cond) * dinv[row]
// 4 waves x 32 rows; B chunk double-buffered in LDS; epilogue repacks acc
// through per-wave LDS slice (stride 132 u16, conflict-free) -> 16B stores.
// ---------------------------------------------------------------------------
template <int K, bool RELU_A, bool ADD_COND>
__global__ __launch_bounds__(256, 2)
void mfma_gemm(const float* __restrict__ A, const u16* __restrict__ P,
               u16* __restrict__ Cbf, const float* __restrict__ condW,
               const int* __restrict__ batch, const float* __restrict__ dinv,
               int M) {
    constexpr int NC = K / 32;
    __shared__ u16 smem[16896];   // [0,16384): B staging (2 bufs); epilogue: 4x4224
    const int t = threadIdx.x;
    const int w = t >> 6;
    const int l = t & 63;
    const int l16 = l & 15;
    const int lq = l >> 4;
    const int m0 = blockIdx.x * 128;

    const int r0 = m0 + w * 32 + l16;
    const int r1 = r0 + 16;
    const bool ok0 = r0 < M, ok1 = r1 < M;
    const float* Ap0 = A + (size_t)(ok0 ? r0 : 0) * K + lq * 8;
    const float* Ap1 = A + (size_t)(ok1 ? r1 : 0) * K + lq * 8;
    const char* Pb = (const char*)P + t * 16;

    f32x4 acc[2][8] = {};

    float4 a00 = make_float4(0.f, 0.f, 0.f, 0.f), a01 = a00, a10 = a00, a11 = a00;
    {
        float4 g0 = *(const float4*)(Pb);
        float4 g1 = *(const float4*)(Pb + 4096);
        float4 g2 = *(const float4*)(Pb + 8192);
        float4 g3 = *(const float4*)(Pb + 12288);
        if (ok0) { a00 = *(const float4*)Ap0; a01 = *(const float4*)(Ap0 + 4); }
        if (ok1) { a10 = *(const float4*)Ap1; a11 = *(const float4*)(Ap1 + 4); }
        *(float4*)&smem[t * 8]        = g0;
        *(float4*)&smem[2048 + t * 8] = g1;
        *(float4*)&smem[4096 + t * 8] = g2;
        *(float4*)&smem[6144 + t * 8] = g3;
    }
    __syncthreads();

    for (int c = 0; c < NC; ++c) {
        const int cur = (c & 1) * 8192, nxt = cur ^ 8192;
        const bool hasNext = (c + 1 < NC);

        float4 g0, g1, g2, g3, n00 = a00, n01 = a01, n10 = a10, n11 = a11;
        if (hasNext) {
            const char* src = Pb + (size_t)(c + 1) * 16384;
            g0 = *(const float4*)(src);
            g1 = *(const float4*)(src + 4096);
            g2 = *(const float4*)(src + 8192);
            g3 = *(const float4*)(src + 12288);
            if (ok0) {
                n00 = *(const float4*)(Ap0 + 32 * (c + 1));
                n01 = *(const float4*)(Ap0 + 32 * (c + 1) + 4);
            }
            if (ok1) {
                n10 = *(const float4*)(Ap1 + 32 * (c + 1));
                n11 = *(const float4*)(Ap1 + 32 * (c + 1) + 4);
            }
        }

        bf16x8 bh[8], bl[8];
#pragma unroll
        for (int f = 0; f < 8; f++)
            bh[f] = *(const bf16x8*)&smem[cur + f * 512 + l * 8];
#pragma unroll
        for (int f = 0; f < 8; f++)
            bl[f] = *(const bf16x8*)&smem[cur + 4096 + f * 512 + l * 8];

        SplitA s0 = splitA<RELU_A>(a00, a01);
        SplitA s1 = splitA<RELU_A>(a10, a11);

#pragma unroll
        for (int f = 0; f < 8; f++) {
            acc[0][f] = __builtin_amdgcn_mfma_f32_16x16x32_bf16(s0.h, bh[f], acc[0][f], 0, 0, 0);
            acc[1][f] = __builtin_amdgcn_mfma_f32_16x16x32_bf16(s1.h, bh[f], acc[1][f], 0, 0, 0);
        }
#pragma unroll
        for (int f = 0; f < 8; f++) {
            acc[0][f] = __builtin_amdgcn_mfma_f32_16x16x32_bf16(s0.l, bh[f], acc[0][f], 0, 0, 0);
            acc[1][f] = __builtin_amdgcn_mfma_f32_16x16x32_bf16(s1.l, bh[f], acc[1][f], 0, 0, 0);
        }
#pragma unroll
        for (int f = 0; f < 8; f++) {
            acc[0][f] = __builtin_amdgcn_mfma_f32_16x16x32_bf16(s0.h, bl[f], acc[0][f], 0, 0, 0);
            acc[1][f] = __builtin_amdgcn_mfma_f32_16x16x32_bf16(s1.h, bl[f], acc[1][f], 0, 0, 0);
        }

        if (hasNext) {
            *(float4*)&smem[nxt + t * 8]        = g0;
            *(float4*)&smem[nxt + 2048 + t * 8] = g1;
            *(float4*)&smem[nxt + 4096 + t * 8] = g2;
            *(float4*)&smem[nxt + 6144 + t * 8] = g3;
            a00 = n00; a01 = n01; a10 = n10; a11 = n11;
        }
        __syncthreads();
    }

    // ---- epilogue: scale+cond, pack bf16 via per-wave LDS slice ----
    u16* lds = smem + w * 4224;   // 32 rows x 132 u16
#pragma unroll
    for (int s = 0; s < 2; s++) {
#pragma unroll
        for (int j = 0; j < 4; j++) {
            int rl = s * 16 + lq * 4 + j;
            int grow = m0 + w * 32 + rl;
            int gs = grow < M ? grow : M - 1;
            float scale = dinv[gs];
            int gb = 0;
            if (ADD_COND) gb = batch[gs];
#pragma unroll
            for (int f = 0; f < 8; f++) {
                float v = acc[s][f][j];
                if (ADD_COND) v += condW[gb * HID + f * 16 + l16];
                lds[rl * 132 + f * 16 + l16] = f2bf(v * scale);
            }
        }
    }
    // readback (compiler inserts lgkmcnt for same-wave RAW) + 16B stores
#pragma unroll
    for (int pass = 0; pass < 8; pass++) {
        int row = pass * 4 + lq;                       // lq = l>>4: 0..3
        bf16x8 v = *(const bf16x8*)&lds[row * 132 + l16 * 8];
        *(bf16x8*)&Cbf[(size_t)(m0 + w * 32 + row) * HID + l16 * 8] = v;
    }
}

// ---------------------------------------------------------------------------
// gather aggregation over packed-bf16 u:
//   o[d] = bias + dinv[d]*(u[d] + sum u[src]);  FUSE_OUT: logits via Wout
// ---------------------------------------------------------------------------
template <bool FUSE_OUT>
__global__ __launch_bounds__(256)
void agg_gather(const u32* __restrict__ u, const float* __restrict__ dinv,
                const int* __restrict__ row_start, const int* __restrict__ csr_src,
                const float* __restrict__ bias, float* __restrict__ out,
                const float* __restrict__ Wout, const float* __restrict__ bout,
                float* __restrict__ logits) {
    int node = blockIdx.x * 4 + (threadIdx.x >> 6);
    int lane = threadIdx.x & 63;
    if (node >= NN) return;
    int p = row_start[node], pend = row_start[node + 1];
    u32 pv = u[(size_t)node * 64 + lane];
    float ax = __builtin_bit_cast(float, pv << 16);
    float ay = __builtin_bit_cast(float, pv & 0xFFFF0000u);
    int s = (p < pend) ? csr_src[p] : 0;
    while (p < pend) {
        int sn = (p + 1 < pend) ? csr_src[p + 1] : 0;
        u32 v = u[(size_t)s * 64 + lane];
        ax += __builtin_bit_cast(float, v << 16);
        ay += __builtin_bit_cast(float, v & 0xFFFF0000u);
        s = sn;
        ++p;
    }
    float dd = dinv[node];
    float2 bb = *(const float2*)&bias[lane * 2];
    float ox = fmaf(dd, ax, bb.x);
    float oy = fmaf(dd, ay, bb.y);
    if (FUSE_OUT) {
        float2 wv = *(const float2*)&Wout[lane * 2];
        float v = fmaxf(ox, 0.f) * wv.x + fmaxf(oy, 0.f) * wv.y;
#pragma unroll
        for (int o = 32; o; o >>= 1) v += __shfl_down(v, o);
        if (lane == 0) logits[node] = v + bout[0];
    } else {
        float2 o;
        o.x = ox;
        o.y = oy;
        *(float2*)&out[(size_t)node * HID + lane * 2] = o;
    }
}

// ---------------------------------------------------------------------------
extern "C" void kernel_launch(void* const* d_in, const int* in_sizes, int n_in,
                              void* d_out, int out_size, void* d_ws, size_t ws_size,
                              hipStream_t stream) {
    const float* x     = (const float*)d_in[0];
    const int*   ei    = (const int*)d_in[1];
    const float* se    = (const float*)d_in[2];
    const int*   batch = (const int*)d_in[3];
    const float* W1    = (const float*)d_in[4];
    const float* b1    = (const float*)d_in[5];
    const float* W2    = (const float*)d_in[6];
    const float* b2    = (const float*)d_in[7];
    const float* Wout  = (const float*)d_in[8];
    const float* bout  = (const float*)d_in[9];
    float* logits = (float*)d_out;

    const int* srcp = ei;
    const int* dstp = ei + NE;

    // workspace carve (float offsets; 16B-aligned)
    float* ws       = (float*)d_ws;
    float* dinv     = ws;                        // 50176
    float* condW    = ws + 50176;                // 8192
    u16*   W1p      = (u16*)(ws + 58368);        // 98304 f
    u16*   W2p      = (u16*)(ws + 156672);       // 16384 f
    int*   counts   = (int*)(ws + 173056);       // 50176 (reused as cursor)
    int*   row_st   = (int*)(ws + 223232);       // 50176
    int*   csr_src  = (int*)(ws + 273408);       // 600000
    int*   bsum     = (int*)(ws + 873408);       // 256
    float* bufA     = ws + 873664;               // NNP*128 f region (u1/u2 bf16 packed)
    float* bufB     = bufA + (size_t)NNP * HID;  // NNP*128 f region (h1 fp32)

    u16* ubf  = (u16*)bufA;      // packed bf16 u (both layers)
    const int NB = (NN + 255) / 256;  // 196

    // degree + CSR build
    hipMemsetAsync(counts, 0, NN * sizeof(int), stream);
    deg_count<<<(NE + 255) / 256, 256, 0, stream>>>(dstp, counts);
    pscan1<<<NB, 256, 0, stream>>>(counts, row_st, bsum, dinv);
    pscan2<<<1, 256, 0, stream>>>(bsum, NB);
    pscan3<<<NB, 256, 0, stream>>>(row_st, bsum, counts);
    csr_fill<<<(NE + 255) / 256, 256, 0, stream>>>(srcp, dstp, counts, csr_src);

    // weight prep
    cond_gemm<<<NG, 512, 0, stream>>>(se, W1, condW);
    wt_pack<<<(24 * 512 + 255) / 256, 256, 0, stream>>>(W1, W1p, INCH);
    wt_pack<<<(4 * 512 + 255) / 256, 256, 0, stream>>>(W2, W2p, HID);

    // layer 1: u1(bf16) = (x @ W1[:768] + condW[batch]) * dinv
    mfma_gemm<INCH, false, true><<<(NN + 127) / 128, 256, 0, stream>>>(
        x, W1p, ubf, condW, batch, dinv, NN);
    agg_gather<false><<<(NN + 3) / 4, 256, 0, stream>>>(
        (const u32*)ubf, dinv, row_st, csr_src, b1, bufB, nullptr, nullptr, nullptr);

    // layer 2: u2(bf16) = (relu(h1) @ W2) * dinv ; gather + fused head
    mfma_gemm<HID, true, false><<<(NN + 127) / 128, 256, 0, stream>>>(
        bufB, W2p, ubf, nullptr, nullptr, dinv, NN);
    agg_gather<true><<<(NN + 3) / 4, 256, 0, stream>>>(
        (const u32*)ubf, dinv, row_st, csr_src, b2, nullptr, Wout, bout, logits);
}